// Round 7
// baseline (2089.169 us; speedup 1.0000x reference)
//
#include <hip/hip_runtime.h>
#include <hip/hip_fp16.h>

#define NN 100000
#define NE 1600000
#define FIN 128
#define HD 64
#define CO 40
#define NG 2048
#define NBUK 782          // ceil(NN/128)

// ---------------- histogram of dst (in-degree) ----------------
__global__ __launch_bounds__(256) void hist_kernel(const int* __restrict__ dst, int* __restrict__ degi) {
    int e = blockIdx.x * 256 + threadIdx.x;
    if (e < NE) atomicAdd(&degi[dst[e]], 1);
}

// ---------------- di = rsqrt(deg+1) ----------------
__global__ __launch_bounds__(256) void di_kernel(const int* __restrict__ degi, float* __restrict__ di) {
    int i = blockIdx.x * 256 + threadIdx.x;
    if (i < NN) di[i] = rsqrtf((float)degi[i] + 1.0f);
}

// ---------------- per-bucket degree sum (128 nodes/bucket) ----------------
__global__ __launch_bounds__(128) void csum_kernel(const int* __restrict__ degi, int* __restrict__ csum) {
    int i = blockIdx.x * 128 + threadIdx.x;
    int v = (i < NN) ? degi[i] : 0;
#pragma unroll
    for (int o = 32; o > 0; o >>= 1) v += __shfl_xor(v, o, 64);
    __shared__ int ws2[2];
    if ((threadIdx.x & 63) == 0) ws2[threadIdx.x >> 6] = v;
    __syncthreads();
    if (threadIdx.x == 0) csum[blockIdx.x] = ws2[0] + ws2[1];
}

// ---------------- scan 782 bucket sums -> cbase (exclusive), ccur copy ----------------
__global__ __launch_bounds__(1024) void cscan_kernel(const int* __restrict__ csum,
                                                     int* __restrict__ cbase,
                                                     int* __restrict__ ccur) {
    __shared__ int s[1024];
    int t = threadIdx.x;
    int v = (t < NBUK) ? csum[t] : 0;
    s[t] = v;
    __syncthreads();
    for (int off = 1; off < 1024; off <<= 1) {
        int x = (t >= off) ? s[t - off] : 0;
        __syncthreads();
        s[t] += x;
        __syncthreads();
    }
    if (t < NBUK) { int e = s[t] - v; cbase[t] = e; ccur[t] = e; }
    if (t == 0) cbase[NBUK] = NE;
}

// ---------------- coarse scatter: tmp[pos] = (dst&127)<<17 | src ----------------
__global__ __launch_bounds__(256) void scatter_coarse(const int* __restrict__ src,
                                                      const int* __restrict__ dst,
                                                      int* __restrict__ ccur,
                                                      unsigned int* __restrict__ tmp) {
    int e = blockIdx.x * 256 + threadIdx.x;
    if (e >= NE) return;
    int d = dst[e];
    int s = src[e];
    int b = d >> 7;
    int pos = atomicAdd(&ccur[b], 1);
    tmp[pos] = ((unsigned int)(d & 127) << 17) | (unsigned int)s;
}

// ---------------- W_eff = pre_w @ c1_w ; b_eff = pre_b @ c1_w ----------------
__global__ __launch_bounds__(256) void weff_kernel(const float* __restrict__ pre_w,
                                                   const float* __restrict__ pre_b,
                                                   const float* __restrict__ c1_w,
                                                   float* __restrict__ weff,
                                                   float* __restrict__ beff) {
    if (blockIdx.x < 32) {
        int o = blockIdx.x * 256 + threadIdx.x;  // [0, 8192)
        int r = o >> 6, c = o & 63;
        float acc = 0.0f;
#pragma unroll 8
        for (int k = 0; k < HD; k++) acc = fmaf(pre_w[r * HD + k], c1_w[k * HD + c], acc);
        weff[o] = acc;
    } else {
        int c = threadIdx.x;
        if (c < HD) {
            float acc = 0.0f;
#pragma unroll 8
            for (int k = 0; k < HD; k++) acc = fmaf(pre_b[k], c1_w[k * HD + c], acc);
            beff[c] = acc;
        }
    }
}

// =====================================================================
// Tiled GEMM 1: hws = half((x @ W_eff + b_eff) * di)   [N,128]@[128,64]
// =====================================================================
__global__ __launch_bounds__(256) void gemm1_tiled(const float* __restrict__ x,
                                                   const float* __restrict__ w,
                                                   const float* __restrict__ b,
                                                   const float* __restrict__ di,
                                                   __half* __restrict__ hws) {
    __shared__ float wS[FIN * HD];   // 32 KB, [k][f]
    __shared__ float xS[64 * FIN];   // 32 KB, swizzled transpose
    int tid = threadIdx.x;
    for (int i = tid; i < FIN * HD; i += 256) wS[i] = w[i];
    int tn = tid & 15, tf = tid >> 4;
    int f0 = tf * 4;
    float4 bv = ((const float4*)b)[tf];
    int ntiles = (NN + 63) >> 6;  // 1563
    for (int t = blockIdx.x; t < ntiles; t += gridDim.x) {
        int nb = t << 6;
        __syncthreads();
        {   // stage x tile transposed+swizzled
            int n_l = tid >> 5;   // 0..7
            int k4 = tid & 31;    // 0..31
            for (int r = 0; r < 8; r++) {
                int n = n_l + r * 8;
                int row = nb + n;
                float4 v = make_float4(0.f, 0.f, 0.f, 0.f);
                if (row < NN) v = ((const float4*)(x + (size_t)row * FIN))[k4];
                int g = n >> 2, nl2 = n & 3;
                const float* vp = (const float*)&v;
#pragma unroll
                for (int j = 0; j < 4; j++) {
                    int k = k4 * 4 + j;
                    int gp = g ^ (k & 15);
                    xS[k * 64 + gp * 4 + nl2] = vp[j];
                }
            }
        }
        __syncthreads();
        float acc[4][4];
#pragma unroll
        for (int i = 0; i < 4; i++)
#pragma unroll
            for (int j = 0; j < 4; j++) acc[i][j] = 0.0f;
#pragma unroll 4
        for (int k = 0; k < FIN; k++) {
            int gp = tn ^ (k & 15);
            float4 xv = *(const float4*)&xS[k * 64 + gp * 4];
            float4 wv = *(const float4*)&wS[k * 64 + f0];
            acc[0][0] = fmaf(xv.x, wv.x, acc[0][0]); acc[0][1] = fmaf(xv.x, wv.y, acc[0][1]);
            acc[0][2] = fmaf(xv.x, wv.z, acc[0][2]); acc[0][3] = fmaf(xv.x, wv.w, acc[0][3]);
            acc[1][0] = fmaf(xv.y, wv.x, acc[1][0]); acc[1][1] = fmaf(xv.y, wv.y, acc[1][1]);
            acc[1][2] = fmaf(xv.y, wv.z, acc[1][2]); acc[1][3] = fmaf(xv.y, wv.w, acc[1][3]);
            acc[2][0] = fmaf(xv.z, wv.x, acc[2][0]); acc[2][1] = fmaf(xv.z, wv.y, acc[2][1]);
            acc[2][2] = fmaf(xv.z, wv.z, acc[2][2]); acc[2][3] = fmaf(xv.z, wv.w, acc[2][3]);
            acc[3][0] = fmaf(xv.w, wv.x, acc[3][0]); acc[3][1] = fmaf(xv.w, wv.y, acc[3][1]);
            acc[3][2] = fmaf(xv.w, wv.z, acc[3][2]); acc[3][3] = fmaf(xv.w, wv.w, acc[3][3]);
        }
        int n0 = nb + tn * 4;
#pragma unroll
        for (int i = 0; i < 4; i++) {
            int n = n0 + i;
            if (n < NN) {
                float dn = di[n];
                __half2 p0 = __floats2half2_rn((acc[i][0] + bv.x) * dn, (acc[i][1] + bv.y) * dn);
                __half2 p1 = __floats2half2_rn((acc[i][2] + bv.z) * dn, (acc[i][3] + bv.w) * dn);
                __half2* o = (__half2*)(hws + (size_t)n * HD + f0);
                o[0] = p0; o[1] = p1;
            }
        }
    }
}

// =====================================================================
// Tiled GEMM 2: hws = half((h1 @ c2_w) * di)   [N,64]@[64,64]
// =====================================================================
__global__ __launch_bounds__(256) void conv_gemm_tiled(const float* __restrict__ hin,
                                                       const float* __restrict__ w,
                                                       const float* __restrict__ di,
                                                       __half* __restrict__ hws) {
    __shared__ float wS[HD * HD];   // 16 KB
    __shared__ float xS[64 * HD];   // 16 KB
    int tid = threadIdx.x;
    for (int i = tid; i < HD * HD; i += 256) wS[i] = w[i];
    int tn = tid & 15, tf = tid >> 4;
    int f0 = tf * 4;
    int ntiles = (NN + 63) >> 6;
    for (int t = blockIdx.x; t < ntiles; t += gridDim.x) {
        int nb = t << 6;
        __syncthreads();
        {
            int n_l = tid >> 4;   // 0..15
            int k4 = tid & 15;    // 0..15
            for (int r = 0; r < 4; r++) {
                int n = n_l + r * 16;
                int row = nb + n;
                float4 v = make_float4(0.f, 0.f, 0.f, 0.f);
                if (row < NN) v = ((const float4*)(hin + (size_t)row * HD))[k4];
                int g = n >> 2, nl2 = n & 3;
                const float* vp = (const float*)&v;
#pragma unroll
                for (int j = 0; j < 4; j++) {
                    int k = k4 * 4 + j;
                    int gp = g ^ (k & 15);
                    xS[k * 64 + gp * 4 + nl2] = vp[j];
                }
            }
        }
        __syncthreads();
        float acc[4][4];
#pragma unroll
        for (int i = 0; i < 4; i++)
#pragma unroll
            for (int j = 0; j < 4; j++) acc[i][j] = 0.0f;
#pragma unroll 4
        for (int k = 0; k < HD; k++) {
            int gp = tn ^ (k & 15);
            float4 xv = *(const float4*)&xS[k * 64 + gp * 4];
            float4 wv = *(const float4*)&wS[k * 64 + f0];
            acc[0][0] = fmaf(xv.x, wv.x, acc[0][0]); acc[0][1] = fmaf(xv.x, wv.y, acc[0][1]);
            acc[0][2] = fmaf(xv.x, wv.z, acc[0][2]); acc[0][3] = fmaf(xv.x, wv.w, acc[0][3]);
            acc[1][0] = fmaf(xv.y, wv.x, acc[1][0]); acc[1][1] = fmaf(xv.y, wv.y, acc[1][1]);
            acc[1][2] = fmaf(xv.y, wv.z, acc[1][2]); acc[1][3] = fmaf(xv.y, wv.w, acc[1][3]);
            acc[2][0] = fmaf(xv.z, wv.x, acc[2][0]); acc[2][1] = fmaf(xv.z, wv.y, acc[2][1]);
            acc[2][2] = fmaf(xv.z, wv.z, acc[2][2]); acc[2][3] = fmaf(xv.z, wv.w, acc[2][3]);
            acc[3][0] = fmaf(xv.w, wv.x, acc[3][0]); acc[3][1] = fmaf(xv.w, wv.y, acc[3][1]);
            acc[3][2] = fmaf(xv.w, wv.z, acc[3][2]); acc[3][3] = fmaf(xv.w, wv.w, acc[3][3]);
        }
        int n0 = nb + tn * 4;
#pragma unroll
        for (int i = 0; i < 4; i++) {
            int n = n0 + i;
            if (n < NN) {
                float dn = di[n];
                __half2 p0 = __floats2half2_rn(acc[i][0] * dn, acc[i][1] * dn);
                __half2 p1 = __floats2half2_rn(acc[i][2] * dn, acc[i][3] * dn);
                __half2* o = (__half2*)(hws + (size_t)n * HD + f0);
                o[0] = p0; o[1] = p1;
            }
        }
    }
}

// =====================================================================
// Bucket gather: one workgroup per 128-dst bucket. LDS f32 accumulator
// tile [128][64]. A wave processes 2 edges per round: half=lane>>5 picks
// the edge, fl=lane&31 the feature pair (32 lanes x half2 = 64 features).
// All shuffles executed by all 64 lanes (bpermute rule), accumulation
// guarded. Then fused bias+LN+ReLU (+skip+pool for layer 2).
// =====================================================================
__device__ __forceinline__ void bucket_accum(const int* __restrict__ cbase,
                                             const unsigned int* __restrict__ tmp,
                                             const __half* __restrict__ hws,
                                             float* __restrict__ acc,
                                             int b, int lane, int wv) {
    int beg = cbase[b], end = cbase[b + 1];
    int half = lane >> 5;   // which of the 2 edges this round
    int fl = lane & 31;     // feature-pair index: features fl*2, fl*2+1
    for (int cbeg = beg + wv * 64; cbeg < end; cbeg += 256) {
        int cnt = end - cbeg;
        if (cnt > 64) cnt = 64;
        unsigned int el = (lane < cnt) ? tmp[cbeg + lane] : 0u;
        for (int j = 0; j < cnt; j += 2) {
            int jj = j + half;
            unsigned int u = (unsigned int)__shfl((int)el, (jj < cnt) ? jj : 0, 64);
            if (jj < cnt) {
                int dl = (int)(u >> 17);
                int s = (int)(u & 0x1FFFFu);
                __half2 h2 = *(const __half2*)(hws + (size_t)s * HD + fl * 2);
                float2 f2 = __half22float2(h2);
                atomicAdd(&acc[dl * HD + fl * 2], f2.x);
                atomicAdd(&acc[dl * HD + fl * 2 + 1], f2.y);
            }
        }
    }
}

__global__ __launch_bounds__(256) void bucket_gather_ln(const int* __restrict__ cbase,
                                                        const unsigned int* __restrict__ tmp,
                                                        const float* __restrict__ di,
                                                        const __half* __restrict__ hws,
                                                        const float* __restrict__ cb,
                                                        const float* __restrict__ g,
                                                        const float* __restrict__ bb,
                                                        float* __restrict__ out) {
    __shared__ float acc[128 * HD];  // 32 KB
    int b = blockIdx.x;
    int tid = threadIdx.x, lane = tid & 63, wv = tid >> 6;
    for (int i = tid; i < 128 * HD; i += 256) acc[i] = 0.0f;
    __syncthreads();
    bucket_accum(cbase, tmp, hws, acc, b, lane, wv);
    __syncthreads();
    float cbl = cb[lane], gl = g[lane], bbl = bb[lane];
    for (int dl = wv; dl < 128; dl += 4) {
        int node = b * 128 + dl;
        if (node >= NN) break;
        float dn = di[node];
        float self = __half2float(hws[(size_t)node * HD + lane]);
        float v = (acc[dl * HD + lane] + self) * dn + cbl;
        float su = v;
#pragma unroll
        for (int o = 32; o > 0; o >>= 1) su += __shfl_xor(su, o, 64);
        float mu = su * (1.0f / HD);
        float d = v - mu;
        float q = d * d;
#pragma unroll
        for (int o = 32; o > 0; o >>= 1) q += __shfl_xor(q, o, 64);
        float y = d * rsqrtf(q * (1.0f / HD) + 1e-5f) * gl + bbl;
        out[(size_t)node * HD + lane] = fmaxf(y, 0.0f);
    }
}

__global__ __launch_bounds__(256) void bucket_gather_ln_pool(const int* __restrict__ cbase,
                                                             const unsigned int* __restrict__ tmp,
                                                             const float* __restrict__ di,
                                                             const __half* __restrict__ hws,
                                                             const float* __restrict__ cb,
                                                             const float* __restrict__ g,
                                                             const float* __restrict__ bb,
                                                             const float* __restrict__ h1,
                                                             const int* __restrict__ batch,
                                                             float* __restrict__ readout) {
    __shared__ float acc[128 * HD];  // 32 KB
    int b = blockIdx.x;
    int tid = threadIdx.x, lane = tid & 63, wv = tid >> 6;
    for (int i = tid; i < 128 * HD; i += 256) acc[i] = 0.0f;
    __syncthreads();
    bucket_accum(cbase, tmp, hws, acc, b, lane, wv);
    __syncthreads();
    float cbl = cb[lane], gl = g[lane], bbl = bb[lane];
    int curb = -1;
    float runsum = 0.0f;
    for (int dl = wv; dl < 128; dl += 4) {
        int node = b * 128 + dl;
        if (node >= NN) break;
        float dn = di[node];
        float self = __half2float(hws[(size_t)node * HD + lane]);
        float v = (acc[dl * HD + lane] + self) * dn + cbl;
        float su = v;
#pragma unroll
        for (int o = 32; o > 0; o >>= 1) su += __shfl_xor(su, o, 64);
        float mu = su * (1.0f / HD);
        float d = v - mu;
        float q = d * d;
#pragma unroll
        for (int o = 32; o > 0; o >>= 1) q += __shfl_xor(q, o, 64);
        float y = d * rsqrtf(q * (1.0f / HD) + 1e-5f) * gl + bbl;
        float skip = fmaxf(y, 0.0f) + h1[(size_t)node * HD + lane];
        int bn = batch[node];          // wave-uniform
        if (bn != curb) {
            if (curb >= 0) atomicAdd(&readout[(size_t)curb * HD + lane], runsum);
            curb = bn;
            runsum = skip;
        } else {
            runsum += skip;
        }
    }
    if (curb >= 0) atomicAdd(&readout[(size_t)curb * HD + lane], runsum);
}

// ---------------- final: out = readout @ post_w + post_b  [G,64]@[64,40] ----------------
__global__ __launch_bounds__(256) void out_gemm(const float* __restrict__ r,
                                                const float* __restrict__ w,
                                                const float* __restrict__ b,
                                                float* __restrict__ out) {
    __shared__ float lw[HD * CO];
    for (int i = threadIdx.x; i < HD * CO; i += 256) lw[i] = w[i];
    __syncthreads();
    int grp = blockIdx.x * 4 + (threadIdx.x >> 6);
    int c = threadIdx.x & 63;
    if (grp >= NG || c >= CO) return;
    const float* rr = r + (size_t)grp * HD;
    float acc = b[c];
#pragma unroll 8
    for (int k = 0; k < HD; k++) acc = fmaf(rr[k], lw[k * CO + c], acc);
    out[(size_t)grp * CO + c] = acc;
}

extern "C" void kernel_launch(void* const* d_in, const int* in_sizes, int n_in,
                              void* d_out, int out_size, void* d_ws, size_t ws_size,
                              hipStream_t stream) {
    const float* x      = (const float*)d_in[0];
    const int*   ei     = (const int*)d_in[1];
    const int*   batch  = (const int*)d_in[2];
    const float* pre_w  = (const float*)d_in[3];
    const float* pre_b  = (const float*)d_in[4];
    const float* c1_w   = (const float*)d_in[5];
    const float* c1_b   = (const float*)d_in[6];
    const float* n1_g   = (const float*)d_in[7];
    const float* n1_b   = (const float*)d_in[8];
    const float* c2_w   = (const float*)d_in[9];
    const float* c2_b   = (const float*)d_in[10];
    const float* n2_g   = (const float*)d_in[11];
    const float* n2_b   = (const float*)d_in[12];
    const float* post_w = (const float*)d_in[13];
    const float* post_b = (const float*)d_in[14];

    const int* src = ei;
    const int* dst = ei + NE;

    char* p = (char*)d_ws;
    int*          degi    = (int*)p;          p += (size_t)NN * 4;
    int*          csum    = (int*)p;          p += 4096;
    int*          cbase   = (int*)p;          p += 4096;
    int*          ccur    = (int*)p;          p += 4096;
    float*        di      = (float*)p;        p += (size_t)NN * 4;
    float*        weff    = (float*)p;        p += (size_t)FIN * HD * 4;
    float*        beff    = (float*)p;        p += 256;
    unsigned int* tmp     = (unsigned int*)p; p += (size_t)NE * 4;
    float*        h1      = (float*)p;        p += (size_t)NN * HD * 4;
    float*        readout = (float*)p;        p += (size_t)NG * HD * 4;
    __half*       hws     = (__half*)p;       p += (size_t)NN * HD * 2;

    hipMemsetAsync(degi, 0, (size_t)NN * 4, stream);
    hipMemsetAsync(readout, 0, (size_t)NG * HD * 4, stream);

    // degree + coarse CSR
    hist_kernel<<<(NE + 255) / 256, 256, 0, stream>>>(dst, degi);
    di_kernel<<<(NN + 255) / 256, 256, 0, stream>>>(degi, di);
    csum_kernel<<<NBUK, 128, 0, stream>>>(degi, csum);
    cscan_kernel<<<1, 1024, 0, stream>>>(csum, cbase, ccur);
    scatter_coarse<<<(NE + 255) / 256, 256, 0, stream>>>(src, dst, ccur, tmp);

    // Folded pre-MLP weights
    weff_kernel<<<33, 256, 0, stream>>>(pre_w, pre_b, c1_w, weff, beff);

    // layer 1
    gemm1_tiled<<<640, 256, 0, stream>>>(x, weff, beff, di, hws);
    bucket_gather_ln<<<NBUK, 256, 0, stream>>>(cbase, tmp, di, hws, c1_b, n1_g, n1_b, h1);

    // layer 2
    conv_gemm_tiled<<<640, 256, 0, stream>>>(h1, c2_w, di, hws);
    bucket_gather_ln_pool<<<NBUK, 256, 0, stream>>>(cbase, tmp, di, hws, c2_b, n2_g, n2_b, h1, batch, readout);

    out_gemm<<<(NG + 3) / 4, 256, 0, stream>>>(readout, post_w, post_b, (float*)d_out);
}

// Round 8
// 492.613 us; speedup vs baseline: 4.2410x; 4.2410x over previous
//
#include <hip/hip_runtime.h>
#include <hip/hip_fp16.h>

#define NN 100000
#define NE 1600000
#define FIN 128
#define HD 64
#define CO 40
#define NG 2048
#define NBLK1 98   // ceil(100000/1024)

// ---------------- histogram of dst (in-degree) ----------------
__global__ __launch_bounds__(256) void hist_kernel(const int* __restrict__ dst, int* __restrict__ degi) {
    int e = blockIdx.x * 256 + threadIdx.x;
    if (e < NE) atomicAdd(&degi[dst[e]], 1);
}

// ---------------- scan stage 1: per-block (1024 elems) exclusive scan ----------------
__global__ __launch_bounds__(256) void scan1_kernel(const int* __restrict__ degi,
                                                    int* __restrict__ offs,
                                                    int* __restrict__ bsums) {
    __shared__ int s[256];
    int t = threadIdx.x;
    int base = blockIdx.x * 1024 + t * 4;
    int v0 = 0, v1 = 0, v2 = 0, v3 = 0;
    if (base + 0 < NN) v0 = degi[base + 0];
    if (base + 1 < NN) v1 = degi[base + 1];
    if (base + 2 < NN) v2 = degi[base + 2];
    if (base + 3 < NN) v3 = degi[base + 3];
    int sum = v0 + v1 + v2 + v3;
    s[t] = sum;
    __syncthreads();
    for (int off = 1; off < 256; off <<= 1) {
        int x = (t >= off) ? s[t - off] : 0;
        __syncthreads();
        s[t] += x;
        __syncthreads();
    }
    int excl = s[t] - sum;
    if (t == 255) bsums[blockIdx.x] = s[255];
    int run = excl;
    if (base + 0 < NN) { offs[base + 0] = run; run += v0; }
    if (base + 1 < NN) { offs[base + 1] = run; run += v1; }
    if (base + 2 < NN) { offs[base + 2] = run; run += v2; }
    if (base + 3 < NN) { offs[base + 3] = run; run += v3; }
}

// ---------------- scan stage 2: scan the 98 block sums (inclusive) ----------------
__global__ __launch_bounds__(128) void scan2_kernel(int* __restrict__ bsums) {
    __shared__ int s[128];
    int t = threadIdx.x;
    s[t] = (t < NBLK1) ? bsums[t] : 0;
    __syncthreads();
    for (int off = 1; off < 128; off <<= 1) {
        int x = (t >= off) ? s[t - off] : 0;
        __syncthreads();
        s[t] += x;
        __syncthreads();
    }
    if (t < NBLK1) bsums[t] = s[t];
}

// ---------------- scan stage 3: add block prefix; cursor copy + deg_isqrt ----------------
__global__ __launch_bounds__(256) void scan3_kernel(const int* __restrict__ degi,
                                                    int* __restrict__ offs,
                                                    const int* __restrict__ bsums,
                                                    int* __restrict__ cursor,
                                                    float* __restrict__ di) {
    int i = blockIdx.x * 256 + threadIdx.x;
    if (i >= NN) return;
    int b = i >> 10;
    int add = (b > 0) ? bsums[b - 1] : 0;
    int o = offs[i] + add;
    offs[i] = o;
    cursor[i] = o;
    di[i] = rsqrtf((float)degi[i] + 1.0f);
}

// ---------------- build dst-sorted src list ----------------
__global__ __launch_bounds__(256) void build_kernel(const int* __restrict__ src,
                                                    const int* __restrict__ dst,
                                                    int* __restrict__ cursor,
                                                    int* __restrict__ ssrc) {
    int e = blockIdx.x * 256 + threadIdx.x;
    if (e >= NE) return;
    int d = dst[e];
    int pos = atomicAdd(&cursor[d], 1);
    ssrc[pos] = src[e];
}

// ---------------- W_eff = pre_w @ c1_w ; b_eff = pre_b @ c1_w ----------------
__global__ __launch_bounds__(256) void weff_kernel(const float* __restrict__ pre_w,
                                                   const float* __restrict__ pre_b,
                                                   const float* __restrict__ c1_w,
                                                   float* __restrict__ weff,
                                                   float* __restrict__ beff) {
    if (blockIdx.x < 32) {
        int o = blockIdx.x * 256 + threadIdx.x;  // [0, 8192)
        int r = o >> 6, c = o & 63;
        float acc = 0.0f;
#pragma unroll 8
        for (int k = 0; k < HD; k++) acc = fmaf(pre_w[r * HD + k], c1_w[k * HD + c], acc);
        weff[o] = acc;
    } else {
        int c = threadIdx.x;
        if (c < HD) {
            float acc = 0.0f;
#pragma unroll 8
            for (int k = 0; k < HD; k++) acc = fmaf(pre_b[k], c1_w[k * HD + c], acc);
            beff[c] = acc;
        }
    }
}

// =====================================================================
// Tiled GEMM 1: hws = half((x @ W_eff + b_eff) * di)   [N,128]@[128,64]
// 64-node tile; wS + xor-swizzled transposed xS in LDS; 16x16 threads,
// 4n x 4f per thread -> two ds_read_b128 + 16 FMA per k (VALU-bound).
// =====================================================================
__global__ __launch_bounds__(256) void gemm1_tiled(const float* __restrict__ x,
                                                   const float* __restrict__ w,
                                                   const float* __restrict__ b,
                                                   const float* __restrict__ di,
                                                   __half* __restrict__ hws) {
    __shared__ float wS[FIN * HD];   // 32 KB, [k][f]
    __shared__ float xS[64 * FIN];   // 32 KB, swizzled transpose
    int tid = threadIdx.x;
    for (int i = tid; i < FIN * HD; i += 256) wS[i] = w[i];
    int tn = tid & 15, tf = tid >> 4;
    int f0 = tf * 4;
    float4 bv = ((const float4*)b)[tf];
    int ntiles = (NN + 63) >> 6;  // 1563
    for (int t = blockIdx.x; t < ntiles; t += gridDim.x) {
        int nb = t << 6;
        __syncthreads();
        {   // stage x tile transposed+swizzled
            int n_l = tid >> 5;   // 0..7
            int k4 = tid & 31;    // 0..31
            for (int r = 0; r < 8; r++) {
                int n = n_l + r * 8;
                int row = nb + n;
                float4 v = make_float4(0.f, 0.f, 0.f, 0.f);
                if (row < NN) v = ((const float4*)(x + (size_t)row * FIN))[k4];
                int g = n >> 2, nl2 = n & 3;
                const float* vp = (const float*)&v;
#pragma unroll
                for (int j = 0; j < 4; j++) {
                    int k = k4 * 4 + j;
                    int gp = g ^ (k & 15);
                    xS[k * 64 + gp * 4 + nl2] = vp[j];
                }
            }
        }
        __syncthreads();
        float acc[4][4];
#pragma unroll
        for (int i = 0; i < 4; i++)
#pragma unroll
            for (int j = 0; j < 4; j++) acc[i][j] = 0.0f;
#pragma unroll 4
        for (int k = 0; k < FIN; k++) {
            int gp = tn ^ (k & 15);
            float4 xv = *(const float4*)&xS[k * 64 + gp * 4];
            float4 wv = *(const float4*)&wS[k * 64 + f0];
            acc[0][0] = fmaf(xv.x, wv.x, acc[0][0]); acc[0][1] = fmaf(xv.x, wv.y, acc[0][1]);
            acc[0][2] = fmaf(xv.x, wv.z, acc[0][2]); acc[0][3] = fmaf(xv.x, wv.w, acc[0][3]);
            acc[1][0] = fmaf(xv.y, wv.x, acc[1][0]); acc[1][1] = fmaf(xv.y, wv.y, acc[1][1]);
            acc[1][2] = fmaf(xv.y, wv.z, acc[1][2]); acc[1][3] = fmaf(xv.y, wv.w, acc[1][3]);
            acc[2][0] = fmaf(xv.z, wv.x, acc[2][0]); acc[2][1] = fmaf(xv.z, wv.y, acc[2][1]);
            acc[2][2] = fmaf(xv.z, wv.z, acc[2][2]); acc[2][3] = fmaf(xv.z, wv.w, acc[2][3]);
            acc[3][0] = fmaf(xv.w, wv.x, acc[3][0]); acc[3][1] = fmaf(xv.w, wv.y, acc[3][1]);
            acc[3][2] = fmaf(xv.w, wv.z, acc[3][2]); acc[3][3] = fmaf(xv.w, wv.w, acc[3][3]);
        }
        int n0 = nb + tn * 4;
#pragma unroll
        for (int i = 0; i < 4; i++) {
            int n = n0 + i;
            if (n < NN) {
                float dn = di[n];
                __half2 p0 = __floats2half2_rn((acc[i][0] + bv.x) * dn, (acc[i][1] + bv.y) * dn);
                __half2 p1 = __floats2half2_rn((acc[i][2] + bv.z) * dn, (acc[i][3] + bv.w) * dn);
                __half2* o = (__half2*)(hws + (size_t)n * HD + f0);
                o[0] = p0; o[1] = p1;
            }
        }
    }
}

// =====================================================================
// Tiled GEMM 2: hws = half((h1 @ c2_w) * di)   [N,64]@[64,64]
// =====================================================================
__global__ __launch_bounds__(256) void conv_gemm_tiled(const float* __restrict__ hin,
                                                       const float* __restrict__ w,
                                                       const float* __restrict__ di,
                                                       __half* __restrict__ hws) {
    __shared__ float wS[HD * HD];   // 16 KB
    __shared__ float xS[64 * HD];   // 16 KB
    int tid = threadIdx.x;
    for (int i = tid; i < HD * HD; i += 256) wS[i] = w[i];
    int tn = tid & 15, tf = tid >> 4;
    int f0 = tf * 4;
    int ntiles = (NN + 63) >> 6;
    for (int t = blockIdx.x; t < ntiles; t += gridDim.x) {
        int nb = t << 6;
        __syncthreads();
        {
            int n_l = tid >> 4;   // 0..15
            int k4 = tid & 15;    // 0..15
            for (int r = 0; r < 4; r++) {
                int n = n_l + r * 16;
                int row = nb + n;
                float4 v = make_float4(0.f, 0.f, 0.f, 0.f);
                if (row < NN) v = ((const float4*)(hin + (size_t)row * HD))[k4];
                int g = n >> 2, nl2 = n & 3;
                const float* vp = (const float*)&v;
#pragma unroll
                for (int j = 0; j < 4; j++) {
                    int k = k4 * 4 + j;
                    int gp = g ^ (k & 15);
                    xS[k * 64 + gp * 4 + nl2] = vp[j];
                }
            }
        }
        __syncthreads();
        float acc[4][4];
#pragma unroll
        for (int i = 0; i < 4; i++)
#pragma unroll
            for (int j = 0; j < 4; j++) acc[i][j] = 0.0f;
#pragma unroll 4
        for (int k = 0; k < HD; k++) {
            int gp = tn ^ (k & 15);
            float4 xv = *(const float4*)&xS[k * 64 + gp * 4];
            float4 wv = *(const float4*)&wS[k * 64 + f0];
            acc[0][0] = fmaf(xv.x, wv.x, acc[0][0]); acc[0][1] = fmaf(xv.x, wv.y, acc[0][1]);
            acc[0][2] = fmaf(xv.x, wv.z, acc[0][2]); acc[0][3] = fmaf(xv.x, wv.w, acc[0][3]);
            acc[1][0] = fmaf(xv.y, wv.x, acc[1][0]); acc[1][1] = fmaf(xv.y, wv.y, acc[1][1]);
            acc[1][2] = fmaf(xv.y, wv.z, acc[1][2]); acc[1][3] = fmaf(xv.y, wv.w, acc[1][3]);
            acc[2][0] = fmaf(xv.z, wv.x, acc[2][0]); acc[2][1] = fmaf(xv.z, wv.y, acc[2][1]);
            acc[2][2] = fmaf(xv.z, wv.z, acc[2][2]); acc[2][3] = fmaf(xv.z, wv.w, acc[2][3]);
            acc[3][0] = fmaf(xv.w, wv.x, acc[3][0]); acc[3][1] = fmaf(xv.w, wv.y, acc[3][1]);
            acc[3][2] = fmaf(xv.w, wv.z, acc[3][2]); acc[3][3] = fmaf(xv.w, wv.w, acc[3][3]);
        }
        int n0 = nb + tn * 4;
#pragma unroll
        for (int i = 0; i < 4; i++) {
            int n = n0 + i;
            if (n < NN) {
                float dn = di[n];
                __half2 p0 = __floats2half2_rn(acc[i][0] * dn, acc[i][1] * dn);
                __half2 p1 = __floats2half2_rn(acc[i][2] * dn, acc[i][3] * dn);
                __half2* o = (__half2*)(hws + (size_t)n * HD + f0);
                o[0] = p0; o[1] = p1;
            }
        }
    }
}

// =====================================================================
// Gather core (fp16 rows): wave per node, 8 lanes/row (16B each), 8 rows
// per shuffle round. All __shfl executed by all 64 lanes (bpermute rule).
// lane = rsub*8 + fp ; fp in [0,8) covers features fp*8..fp*8+7.
// =====================================================================
__device__ __forceinline__ void gather_half(const int* __restrict__ offs,
                                            const int* __restrict__ ssrc,
                                            const __half* __restrict__ hws,
                                            int node, int lane, int fp, int rsub,
                                            float acc[8]) {
    int beg = offs[node];
    int end = (node + 1 < NN) ? offs[node + 1] : NE;
    union U { float4 f4; __half2 h2[4]; } u;
#pragma unroll
    for (int t = 0; t < 8; t++) acc[t] = 0.0f;
    if (rsub == 0) {  // self-loop term counted once
        u.f4 = ((const float4*)(hws + (size_t)node * HD))[fp];
#pragma unroll
        for (int t = 0; t < 4; t++) {
            float2 p = __half22float2(u.h2[t]);
            acc[2 * t] += p.x; acc[2 * t + 1] += p.y;
        }
    }
    int i = beg;
    while (i < end) {
        int cnt = end - i;
        if (cnt > 64) cnt = 64;
        int sl = (lane < cnt) ? ssrc[i + lane] : 0;
        int j = 0;
        for (; j + 8 <= cnt; j += 8) {
            int s = __shfl(sl, j + rsub, 64);   // non-divergent
            u.f4 = ((const float4*)(hws + (size_t)s * HD))[fp];
#pragma unroll
            for (int t = 0; t < 4; t++) {
                float2 p = __half22float2(u.h2[t]);
                acc[2 * t] += p.x; acc[2 * t + 1] += p.y;
            }
        }
        if (j < cnt) {  // tail 1..7 rows
            int jr = j + rsub;
            int s = __shfl(sl, (jr < cnt) ? jr : 0, 64);  // all lanes execute
            if (jr < cnt) {
                u.f4 = ((const float4*)(hws + (size_t)s * HD))[fp];
#pragma unroll
                for (int t = 0; t < 4; t++) {
                    float2 p = __half22float2(u.h2[t]);
                    acc[2 * t] += p.x; acc[2 * t + 1] += p.y;
                }
            }
        }
        i += cnt;
    }
#pragma unroll
    for (int t = 0; t < 8; t++) {
        acc[t] += __shfl_xor(acc[t], 8, 64);
        acc[t] += __shfl_xor(acc[t], 16, 64);
        acc[t] += __shfl_xor(acc[t], 32, 64);
    }
}

// LN over the 8-features-per-lane layout; returns relu'd y[8].
__device__ __forceinline__ void ln8(float v[8], int fp,
                                    const float* __restrict__ g,
                                    const float* __restrict__ bb,
                                    float y[8]) {
    float su = 0.0f;
#pragma unroll
    for (int t = 0; t < 8; t++) su += v[t];
    su += __shfl_xor(su, 1, 64); su += __shfl_xor(su, 2, 64); su += __shfl_xor(su, 4, 64);
    float mu = su * (1.0f / HD);
    float q = 0.0f;
#pragma unroll
    for (int t = 0; t < 8; t++) { float d = v[t] - mu; q += d * d; }
    q += __shfl_xor(q, 1, 64); q += __shfl_xor(q, 2, 64); q += __shfl_xor(q, 4, 64);
    float rstd = rsqrtf(q * (1.0f / HD) + 1e-5f);
    float4 ga = ((const float4*)g)[fp * 2], gb = ((const float4*)g)[fp * 2 + 1];
    float4 ba = ((const float4*)bb)[fp * 2], bc = ((const float4*)bb)[fp * 2 + 1];
    float gv[8] = {ga.x, ga.y, ga.z, ga.w, gb.x, gb.y, gb.z, gb.w};
    float bv[8] = {ba.x, ba.y, ba.z, ba.w, bc.x, bc.y, bc.z, bc.w};
#pragma unroll
    for (int t = 0; t < 8; t++) y[t] = fmaxf((v[t] - mu) * rstd * gv[t] + bv[t], 0.0f);
}

// ---------------- layer-1 gather + bias + LN + ReLU -> h1 (f32) ----------------
__global__ __launch_bounds__(256) void gather_ln(const int* __restrict__ offs,
                                                 const int* __restrict__ ssrc,
                                                 const float* __restrict__ di,
                                                 const __half* __restrict__ hws,
                                                 const float* __restrict__ cb,
                                                 const float* __restrict__ g,
                                                 const float* __restrict__ bb,
                                                 float* __restrict__ out) {
    int wv = threadIdx.x >> 6;
    int lane = threadIdx.x & 63;
    int fp = lane & 7, rsub = lane >> 3;
    int node = blockIdx.x * 4 + wv;      // NN % 4 == 0
    float acc[8];
    gather_half(offs, ssrc, hws, node, lane, fp, rsub, acc);
    float dn = di[node];
    float4 ca = ((const float4*)cb)[fp * 2], cc = ((const float4*)cb)[fp * 2 + 1];
    float cv[8] = {ca.x, ca.y, ca.z, ca.w, cc.x, cc.y, cc.z, cc.w};
    float v[8], y[8];
#pragma unroll
    for (int t = 0; t < 8; t++) v[t] = acc[t] * dn + cv[t];
    ln8(v, fp, g, bb, y);
    if (rsub == 0) {
        float4 o0 = {y[0], y[1], y[2], y[3]};
        float4 o1 = {y[4], y[5], y[6], y[7]};
        float* row = out + (size_t)node * HD + fp * 8;
        ((float4*)row)[0] = o0;
        ((float4*)row)[1] = o1;
    }
}

// ---------------- layer-2 gather + LN + ReLU + skip + pooled scatter ----------------
__global__ __launch_bounds__(256) void gather_ln_pool(const int* __restrict__ offs,
                                                      const int* __restrict__ ssrc,
                                                      const float* __restrict__ di,
                                                      const __half* __restrict__ hws,
                                                      const float* __restrict__ cb,
                                                      const float* __restrict__ g,
                                                      const float* __restrict__ bb,
                                                      const float* __restrict__ h1,
                                                      const int* __restrict__ batch,
                                                      float* __restrict__ readout) {
    __shared__ float ls[4][HD];
    __shared__ int lb[4];
    int wv = threadIdx.x >> 6;
    int lane = threadIdx.x & 63;
    int fp = lane & 7, rsub = lane >> 3;
    int node = blockIdx.x * 4 + wv;
    float acc[8];
    gather_half(offs, ssrc, hws, node, lane, fp, rsub, acc);
    float dn = di[node];
    float4 ca = ((const float4*)cb)[fp * 2], cc = ((const float4*)cb)[fp * 2 + 1];
    float cv[8] = {ca.x, ca.y, ca.z, ca.w, cc.x, cc.y, cc.z, cc.w};
    float v[8], y[8];
#pragma unroll
    for (int t = 0; t < 8; t++) v[t] = acc[t] * dn + cv[t];
    ln8(v, fp, g, bb, y);
    if (rsub == 0) {
        const float* h1row = h1 + (size_t)node * HD + fp * 8;
        float4 h0 = ((const float4*)h1row)[0];
        float4 h1v = ((const float4*)h1row)[1];
        float4 s0 = {y[0] + h0.x, y[1] + h0.y, y[2] + h0.z, y[3] + h0.w};
        float4 s1 = {y[4] + h1v.x, y[5] + h1v.y, y[6] + h1v.z, y[7] + h1v.w};
        float* lrow = &ls[wv][fp * 8];
        ((float4*)lrow)[0] = s0;
        ((float4*)lrow)[1] = s1;
    }
    if (lane == 0) lb[wv] = batch[node];
    __syncthreads();
    int f = lane;
    bool same = (lb[0] == lb[1]) && (lb[1] == lb[2]) && (lb[2] == lb[3]);
    if (same) {
        if (wv == 0) {
            float s4 = ls[0][f] + ls[1][f] + ls[2][f] + ls[3][f];
            atomicAdd(&readout[(size_t)lb[0] * HD + f], s4);
        }
    } else {
        atomicAdd(&readout[(size_t)lb[wv] * HD + f], ls[wv][f]);
    }
}

// ---------------- final: out = readout @ post_w + post_b  [G,64]@[64,40] ----------------
__global__ __launch_bounds__(256) void out_gemm(const float* __restrict__ r,
                                                const float* __restrict__ w,
                                                const float* __restrict__ b,
                                                float* __restrict__ out) {
    __shared__ float lw[HD * CO];
    for (int i = threadIdx.x; i < HD * CO; i += 256) lw[i] = w[i];
    __syncthreads();
    int grp = blockIdx.x * 4 + (threadIdx.x >> 6);
    int c = threadIdx.x & 63;
    if (grp >= NG || c >= CO) return;
    const float* rr = r + (size_t)grp * HD;
    float acc = b[c];
#pragma unroll 8
    for (int k = 0; k < HD; k++) acc = fmaf(rr[k], lw[k * CO + c], acc);
    out[(size_t)grp * CO + c] = acc;
}

extern "C" void kernel_launch(void* const* d_in, const int* in_sizes, int n_in,
                              void* d_out, int out_size, void* d_ws, size_t ws_size,
                              hipStream_t stream) {
    const float* x      = (const float*)d_in[0];
    const int*   ei     = (const int*)d_in[1];
    const int*   batch  = (const int*)d_in[2];
    const float* pre_w  = (const float*)d_in[3];
    const float* pre_b  = (const float*)d_in[4];
    const float* c1_w   = (const float*)d_in[5];
    const float* c1_b   = (const float*)d_in[6];
    const float* n1_g   = (const float*)d_in[7];
    const float* n1_b   = (const float*)d_in[8];
    const float* c2_w   = (const float*)d_in[9];
    const float* c2_b   = (const float*)d_in[10];
    const float* n2_g   = (const float*)d_in[11];
    const float* n2_b   = (const float*)d_in[12];
    const float* post_w = (const float*)d_in[13];
    const float* post_b = (const float*)d_in[14];

    const int* src = ei;
    const int* dst = ei + NE;

    char* p = (char*)d_ws;
    int*    degi    = (int*)p;                p += (size_t)NN * 4;
    int*    offs    = (int*)p;                p += (size_t)NN * 4;
    int*    cursor  = (int*)p;                p += (size_t)NN * 4;
    int*    bsums   = (int*)p;                p += 512;
    float*  di      = (float*)p;              p += (size_t)NN * 4;
    float*  weff    = (float*)p;              p += (size_t)FIN * HD * 4;
    float*  beff    = (float*)p;              p += 256;
    int*    ssrc    = (int*)p;                p += (size_t)NE * 4;
    float*  h1      = (float*)p;              p += (size_t)NN * HD * 4;
    float*  readout = (float*)p;              p += (size_t)NG * HD * 4;
    __half* hws     = (__half*)p;             p += (size_t)NN * HD * 2;

    hipMemsetAsync(degi, 0, (size_t)NN * 4, stream);
    hipMemsetAsync(readout, 0, (size_t)NG * HD * 4, stream);

    // CSR build (shared by both layers)
    hist_kernel<<<(NE + 255) / 256, 256, 0, stream>>>(dst, degi);
    scan1_kernel<<<NBLK1, 256, 0, stream>>>(degi, offs, bsums);
    scan2_kernel<<<1, 128, 0, stream>>>(bsums);
    scan3_kernel<<<(NN + 255) / 256, 256, 0, stream>>>(degi, offs, bsums, cursor, di);
    build_kernel<<<(NE + 255) / 256, 256, 0, stream>>>(src, dst, cursor, ssrc);

    // Folded pre-MLP weights
    weff_kernel<<<33, 256, 0, stream>>>(pre_w, pre_b, c1_w, weff, beff);

    // layer 1
    gemm1_tiled<<<640, 256, 0, stream>>>(x, weff, beff, di, hws);
    gather_ln<<<NN / 4, 256, 0, stream>>>(offs, ssrc, di, hws, c1_b, n1_g, n1_b, h1);

    // layer 2
    conv_gemm_tiled<<<640, 256, 0, stream>>>(h1, c2_w, di, hws);
    gather_ln_pool<<<NN / 4, 256, 0, stream>>>(offs, ssrc, di, hws, c2_b, n2_g, n2_b, h1, batch, readout);

    out_gemm<<<(NG + 3) / 4, 256, 0, stream>>>(readout, post_w, post_b, (float*)d_out);
}

// Round 9
// 379.174 us; speedup vs baseline: 5.5098x; 1.2992x over previous
//
#include <hip/hip_runtime.h>
#include <hip/hip_fp16.h>

#define NN 100000
#define NE 1600000
#define FIN 128
#define HD 64
#define CO 40
#define NG 2048
#define NBUK 782          // ceil(NN/128)
#define BCAP 3072         // bucket capacity (mean 2046, 22 sigma margin)

// ---------------- init padded cursors ----------------
__global__ __launch_bounds__(256) void init_kernel(int* __restrict__ ccur) {
    int b = blockIdx.x * 256 + threadIdx.x;
    if (b < NBUK) ccur[b * 16] = b * BCAP;
}

// ---------------- coarse scatter: tmp[pos] = (dst&127)<<17 | src ----------------
__global__ __launch_bounds__(256) void scatter_coarse(const int* __restrict__ src,
                                                      const int* __restrict__ dst,
                                                      int* __restrict__ ccur,
                                                      unsigned int* __restrict__ tmp) {
    int e = blockIdx.x * 256 + threadIdx.x;
    if (e >= NE) return;
    int d = dst[e];
    int s = src[e];
    int b = d >> 7;
    int pos = atomicAdd(&ccur[b * 16], 1);   // pos is global (base b*BCAP baked in)
    tmp[pos] = ((unsigned int)(d & 127) << 17) | (unsigned int)s;
}

// ---------------- per-bucket counting sort -> dense ssrc + offs/degn/di ----------------
__global__ __launch_bounds__(256) void bucket_sort(const int* __restrict__ ccur,
                                                   const unsigned int* __restrict__ tmp,
                                                   unsigned int* __restrict__ ssrc,
                                                   int* __restrict__ offs,
                                                   int* __restrict__ degn,
                                                   float* __restrict__ di) {
    __shared__ int lh[128];        // per-node counts
    __shared__ int ls[128];        // inclusive scan
    __shared__ int lcur[128];      // running cursors (bucket-local)
    __shared__ unsigned int lsorted[BCAP];
    int b = blockIdx.x;
    int tid = threadIdx.x;
    int base = b * BCAP;
    int cnt = ccur[b * 16] - base;
    if (tid < 128) lh[tid] = 0;
    __syncthreads();
    for (int i = tid; i < cnt; i += 256) {
        unsigned int u = tmp[base + i];
        atomicAdd(&lh[(u >> 17) & 127], 1);
    }
    __syncthreads();
    if (tid < 128) ls[tid] = lh[tid];
    __syncthreads();
    for (int off = 1; off < 128; off <<= 1) {
        int v = 0;
        if (tid < 128 && tid >= off) v = ls[tid - off];
        __syncthreads();
        if (tid < 128) ls[tid] += v;
        __syncthreads();
    }
    if (tid < 128) {
        int excl = ls[tid] - lh[tid];
        lcur[tid] = excl;
        int node = b * 128 + tid;
        if (node < NN) {
            offs[node] = base + excl;
            degn[node] = lh[tid];
            di[node] = rsqrtf((float)lh[tid] + 1.0f);
        }
    }
    __syncthreads();
    for (int i = tid; i < cnt; i += 256) {
        unsigned int u = tmp[base + i];
        int dl = (u >> 17) & 127;
        int pos = atomicAdd(&lcur[dl], 1);
        lsorted[pos] = u & 0x1FFFFu;
    }
    __syncthreads();
    for (int i = tid; i < cnt; i += 256) ssrc[base + i] = lsorted[i];  // dense, coalesced
}

// ---------------- W_eff = pre_w @ c1_w ; b_eff = pre_b @ c1_w ----------------
__global__ __launch_bounds__(256) void weff_kernel(const float* __restrict__ pre_w,
                                                   const float* __restrict__ pre_b,
                                                   const float* __restrict__ c1_w,
                                                   float* __restrict__ weff,
                                                   float* __restrict__ beff) {
    if (blockIdx.x < 32) {
        int o = blockIdx.x * 256 + threadIdx.x;  // [0, 8192)
        int r = o >> 6, c = o & 63;
        float acc = 0.0f;
#pragma unroll 8
        for (int k = 0; k < HD; k++) acc = fmaf(pre_w[r * HD + k], c1_w[k * HD + c], acc);
        weff[o] = acc;
    } else {
        int c = threadIdx.x;
        if (c < HD) {
            float acc = 0.0f;
#pragma unroll 8
            for (int k = 0; k < HD; k++) acc = fmaf(pre_b[k], c1_w[k * HD + c], acc);
            beff[c] = acc;
        }
    }
}

// =====================================================================
// Tiled GEMM 1: hws = half((x @ W_eff + b_eff) * di)   [N,128]@[128,64]
// Split-K staging: xS holds 64 nodes x 64 k (16 KB) -> LDS 48 KB total.
// =====================================================================
__global__ __launch_bounds__(256) void gemm1_tiled(const float* __restrict__ x,
                                                   const float* __restrict__ w,
                                                   const float* __restrict__ b,
                                                   const float* __restrict__ di,
                                                   __half* __restrict__ hws) {
    __shared__ float wS[FIN * HD];   // 32 KB, [k][f]
    __shared__ float xS[64 * 64];    // 16 KB, swizzled transpose of one K-half
    int tid = threadIdx.x;
    for (int i = tid; i < FIN * HD; i += 256) wS[i] = w[i];
    int tn = tid & 15, tf = tid >> 4;
    int f0 = tf * 4;
    float4 bv = ((const float4*)b)[tf];
    int ntiles = (NN + 63) >> 6;  // 1563
    for (int t = blockIdx.x; t < ntiles; t += gridDim.x) {
        int nb = t << 6;
        float acc[4][4];
#pragma unroll
        for (int i = 0; i < 4; i++)
#pragma unroll
            for (int j = 0; j < 4; j++) acc[i][j] = 0.0f;
        for (int kh = 0; kh < 2; kh++) {
            __syncthreads();
            {   // stage x[nb..nb+63][kh*64 .. kh*64+63] transposed+swizzled
                int n_l = tid >> 4;   // 0..15
                int k4l = tid & 15;   // 0..15
                for (int r = 0; r < 4; r++) {
                    int n = n_l + r * 16;
                    int row = nb + n;
                    float4 v = make_float4(0.f, 0.f, 0.f, 0.f);
                    if (row < NN) v = ((const float4*)(x + (size_t)row * FIN))[kh * 16 + k4l];
                    int g = n >> 2, nl2 = n & 3;
                    const float* vp = (const float*)&v;
#pragma unroll
                    for (int j = 0; j < 4; j++) {
                        int k = k4l * 4 + j;
                        int gp = g ^ (k & 15);
                        xS[k * 64 + gp * 4 + nl2] = vp[j];
                    }
                }
            }
            __syncthreads();
#pragma unroll 4
            for (int kl = 0; kl < 64; kl++) {
                int gp = tn ^ (kl & 15);
                float4 xv = *(const float4*)&xS[kl * 64 + gp * 4];
                float4 wv = *(const float4*)&wS[(kh * 64 + kl) * 64 + f0];
                acc[0][0] = fmaf(xv.x, wv.x, acc[0][0]); acc[0][1] = fmaf(xv.x, wv.y, acc[0][1]);
                acc[0][2] = fmaf(xv.x, wv.z, acc[0][2]); acc[0][3] = fmaf(xv.x, wv.w, acc[0][3]);
                acc[1][0] = fmaf(xv.y, wv.x, acc[1][0]); acc[1][1] = fmaf(xv.y, wv.y, acc[1][1]);
                acc[1][2] = fmaf(xv.y, wv.z, acc[1][2]); acc[1][3] = fmaf(xv.y, wv.w, acc[1][3]);
                acc[2][0] = fmaf(xv.z, wv.x, acc[2][0]); acc[2][1] = fmaf(xv.z, wv.y, acc[2][1]);
                acc[2][2] = fmaf(xv.z, wv.z, acc[2][2]); acc[2][3] = fmaf(xv.z, wv.w, acc[2][3]);
                acc[3][0] = fmaf(xv.w, wv.x, acc[3][0]); acc[3][1] = fmaf(xv.w, wv.y, acc[3][1]);
                acc[3][2] = fmaf(xv.w, wv.z, acc[3][2]); acc[3][3] = fmaf(xv.w, wv.w, acc[3][3]);
            }
        }
        int n0 = nb + tn * 4;
#pragma unroll
        for (int i = 0; i < 4; i++) {
            int n = n0 + i;
            if (n < NN) {
                float dn = di[n];
                __half2 p0 = __floats2half2_rn((acc[i][0] + bv.x) * dn, (acc[i][1] + bv.y) * dn);
                __half2 p1 = __floats2half2_rn((acc[i][2] + bv.z) * dn, (acc[i][3] + bv.w) * dn);
                __half2* o = (__half2*)(hws + (size_t)n * HD + f0);
                o[0] = p0; o[1] = p1;
            }
        }
    }
}

// =====================================================================
// Tiled GEMM 2: hws = half((h1 @ c2_w) * di)   [N,64]@[64,64]
// =====================================================================
__global__ __launch_bounds__(256) void conv_gemm_tiled(const float* __restrict__ hin,
                                                       const float* __restrict__ w,
                                                       const float* __restrict__ di,
                                                       __half* __restrict__ hws) {
    __shared__ float wS[HD * HD];   // 16 KB
    __shared__ float xS[64 * HD];   // 16 KB
    int tid = threadIdx.x;
    for (int i = tid; i < HD * HD; i += 256) wS[i] = w[i];
    int tn = tid & 15, tf = tid >> 4;
    int f0 = tf * 4;
    int ntiles = (NN + 63) >> 6;
    for (int t = blockIdx.x; t < ntiles; t += gridDim.x) {
        int nb = t << 6;
        __syncthreads();
        {
            int n_l = tid >> 4;   // 0..15
            int k4 = tid & 15;    // 0..15
            for (int r = 0; r < 4; r++) {
                int n = n_l + r * 16;
                int row = nb + n;
                float4 v = make_float4(0.f, 0.f, 0.f, 0.f);
                if (row < NN) v = ((const float4*)(hin + (size_t)row * HD))[k4];
                int g = n >> 2, nl2 = n & 3;
                const float* vp = (const float*)&v;
#pragma unroll
                for (int j = 0; j < 4; j++) {
                    int k = k4 * 4 + j;
                    int gp = g ^ (k & 15);
                    xS[k * 64 + gp * 4 + nl2] = vp[j];
                }
            }
        }
        __syncthreads();
        float acc[4][4];
#pragma unroll
        for (int i = 0; i < 4; i++)
#pragma unroll
            for (int j = 0; j < 4; j++) acc[i][j] = 0.0f;
#pragma unroll 4
        for (int k = 0; k < HD; k++) {
            int gp = tn ^ (k & 15);
            float4 xv = *(const float4*)&xS[k * 64 + gp * 4];
            float4 wv = *(const float4*)&wS[k * 64 + f0];
            acc[0][0] = fmaf(xv.x, wv.x, acc[0][0]); acc[0][1] = fmaf(xv.x, wv.y, acc[0][1]);
            acc[0][2] = fmaf(xv.x, wv.z, acc[0][2]); acc[0][3] = fmaf(xv.x, wv.w, acc[0][3]);
            acc[1][0] = fmaf(xv.y, wv.x, acc[1][0]); acc[1][1] = fmaf(xv.y, wv.y, acc[1][1]);
            acc[1][2] = fmaf(xv.y, wv.z, acc[1][2]); acc[1][3] = fmaf(xv.y, wv.w, acc[1][3]);
            acc[2][0] = fmaf(xv.z, wv.x, acc[2][0]); acc[2][1] = fmaf(xv.z, wv.y, acc[2][1]);
            acc[2][2] = fmaf(xv.z, wv.z, acc[2][2]); acc[2][3] = fmaf(xv.z, wv.w, acc[2][3]);
            acc[3][0] = fmaf(xv.w, wv.x, acc[3][0]); acc[3][1] = fmaf(xv.w, wv.y, acc[3][1]);
            acc[3][2] = fmaf(xv.w, wv.z, acc[3][2]); acc[3][3] = fmaf(xv.w, wv.w, acc[3][3]);
        }
        int n0 = nb + tn * 4;
#pragma unroll
        for (int i = 0; i < 4; i++) {
            int n = n0 + i;
            if (n < NN) {
                float dn = di[n];
                __half2 p0 = __floats2half2_rn(acc[i][0] * dn, acc[i][1] * dn);
                __half2 p1 = __floats2half2_rn(acc[i][2] * dn, acc[i][3] * dn);
                __half2* o = (__half2*)(hws + (size_t)n * HD + f0);
                o[0] = p0; o[1] = p1;
            }
        }
    }
}

// =====================================================================
// Gather core (fp16 rows): wave per node, 8 lanes/row (16B each), 8 rows
// per shuffle round. All __shfl executed by all 64 lanes (bpermute rule).
// =====================================================================
__device__ __forceinline__ void gather_half(const int* __restrict__ offs,
                                            const int* __restrict__ degn,
                                            const unsigned int* __restrict__ ssrc,
                                            const __half* __restrict__ hws,
                                            int node, int lane, int fp, int rsub,
                                            float acc[8]) {
    int beg = offs[node];
    int end = beg + degn[node];
    union U { float4 f4; __half2 h2[4]; } u;
#pragma unroll
    for (int t = 0; t < 8; t++) acc[t] = 0.0f;
    if (rsub == 0) {  // self-loop term counted once
        u.f4 = ((const float4*)(hws + (size_t)node * HD))[fp];
#pragma unroll
        for (int t = 0; t < 4; t++) {
            float2 p = __half22float2(u.h2[t]);
            acc[2 * t] += p.x; acc[2 * t + 1] += p.y;
        }
    }
    int i = beg;
    while (i < end) {
        int cnt = end - i;
        if (cnt > 64) cnt = 64;
        int sl = (lane < cnt) ? (int)ssrc[i + lane] : 0;
        int j = 0;
        for (; j + 8 <= cnt; j += 8) {
            int s = __shfl(sl, j + rsub, 64);   // non-divergent
            u.f4 = ((const float4*)(hws + (size_t)s * HD))[fp];
#pragma unroll
            for (int t = 0; t < 4; t++) {
                float2 p = __half22float2(u.h2[t]);
                acc[2 * t] += p.x; acc[2 * t + 1] += p.y;
            }
        }
        if (j < cnt) {  // tail 1..7 rows
            int jr = j + rsub;
            int s = __shfl(sl, (jr < cnt) ? jr : 0, 64);  // all lanes execute
            if (jr < cnt) {
                u.f4 = ((const float4*)(hws + (size_t)s * HD))[fp];
#pragma unroll
                for (int t = 0; t < 4; t++) {
                    float2 p = __half22float2(u.h2[t]);
                    acc[2 * t] += p.x; acc[2 * t + 1] += p.y;
                }
            }
        }
        i += cnt;
    }
#pragma unroll
    for (int t = 0; t < 8; t++) {
        acc[t] += __shfl_xor(acc[t], 8, 64);
        acc[t] += __shfl_xor(acc[t], 16, 64);
        acc[t] += __shfl_xor(acc[t], 32, 64);
    }
}

// LN over the 8-features-per-lane layout; returns relu'd y[8].
__device__ __forceinline__ void ln8(float v[8], int fp,
                                    const float* __restrict__ g,
                                    const float* __restrict__ bb,
                                    float y[8]) {
    float su = 0.0f;
#pragma unroll
    for (int t = 0; t < 8; t++) su += v[t];
    su += __shfl_xor(su, 1, 64); su += __shfl_xor(su, 2, 64); su += __shfl_xor(su, 4, 64);
    float mu = su * (1.0f / HD);
    float q = 0.0f;
#pragma unroll
    for (int t = 0; t < 8; t++) { float d = v[t] - mu; q += d * d; }
    q += __shfl_xor(q, 1, 64); q += __shfl_xor(q, 2, 64); q += __shfl_xor(q, 4, 64);
    float rstd = rsqrtf(q * (1.0f / HD) + 1e-5f);
    float4 ga = ((const float4*)g)[fp * 2], gb = ((const float4*)g)[fp * 2 + 1];
    float4 ba = ((const float4*)bb)[fp * 2], bc = ((const float4*)bb)[fp * 2 + 1];
    float gv[8] = {ga.x, ga.y, ga.z, ga.w, gb.x, gb.y, gb.z, gb.w};
    float bv[8] = {ba.x, ba.y, ba.z, ba.w, bc.x, bc.y, bc.z, bc.w};
#pragma unroll
    for (int t = 0; t < 8; t++) y[t] = fmaxf((v[t] - mu) * rstd * gv[t] + bv[t], 0.0f);
}

// ---------------- layer-1 gather + bias + LN + ReLU -> h1 (f32) ----------------
__global__ __launch_bounds__(256) void gather_ln(const int* __restrict__ offs,
                                                 const int* __restrict__ degn,
                                                 const unsigned int* __restrict__ ssrc,
                                                 const float* __restrict__ di,
                                                 const __half* __restrict__ hws,
                                                 const float* __restrict__ cb,
                                                 const float* __restrict__ g,
                                                 const float* __restrict__ bb,
                                                 float* __restrict__ out) {
    int wv = threadIdx.x >> 6;
    int lane = threadIdx.x & 63;
    int fp = lane & 7, rsub = lane >> 3;
    int node = blockIdx.x * 4 + wv;      // NN % 4 == 0
    float acc[8];
    gather_half(offs, degn, ssrc, hws, node, lane, fp, rsub, acc);
    float dn = di[node];
    float4 ca = ((const float4*)cb)[fp * 2], cc = ((const float4*)cb)[fp * 2 + 1];
    float cv[8] = {ca.x, ca.y, ca.z, ca.w, cc.x, cc.y, cc.z, cc.w};
    float v[8], y[8];
#pragma unroll
    for (int t = 0; t < 8; t++) v[t] = acc[t] * dn + cv[t];
    ln8(v, fp, g, bb, y);
    if (rsub == 0) {
        float4 o0 = {y[0], y[1], y[2], y[3]};
        float4 o1 = {y[4], y[5], y[6], y[7]};
        float* row = out + (size_t)node * HD + fp * 8;
        ((float4*)row)[0] = o0;
        ((float4*)row)[1] = o1;
    }
}

// ---------------- layer-2 gather + LN + ReLU + skip + pooled scatter ----------------
__global__ __launch_bounds__(256) void gather_ln_pool(const int* __restrict__ offs,
                                                      const int* __restrict__ degn,
                                                      const unsigned int* __restrict__ ssrc,
                                                      const float* __restrict__ di,
                                                      const __half* __restrict__ hws,
                                                      const float* __restrict__ cb,
                                                      const float* __restrict__ g,
                                                      const float* __restrict__ bb,
                                                      const float* __restrict__ h1,
                                                      const int* __restrict__ batch,
                                                      float* __restrict__ readout) {
    __shared__ float ls[4][HD];
    __shared__ int lb[4];
    int wv = threadIdx.x >> 6;
    int lane = threadIdx.x & 63;
    int fp = lane & 7, rsub = lane >> 3;
    int node = blockIdx.x * 4 + wv;
    float acc[8];
    gather_half(offs, degn, ssrc, hws, node, lane, fp, rsub, acc);
    float dn = di[node];
    float4 ca = ((const float4*)cb)[fp * 2], cc = ((const float4*)cb)[fp * 2 + 1];
    float cv[8] = {ca.x, ca.y, ca.z, ca.w, cc.x, cc.y, cc.z, cc.w};
    float v[8], y[8];
#pragma unroll
    for (int t = 0; t < 8; t++) v[t] = acc[t] * dn + cv[t];
    ln8(v, fp, g, bb, y);
    if (rsub == 0) {
        const float* h1row = h1 + (size_t)node * HD + fp * 8;
        float4 h0 = ((const float4*)h1row)[0];
        float4 h1v = ((const float4*)h1row)[1];
        float4 s0 = {y[0] + h0.x, y[1] + h0.y, y[2] + h0.z, y[3] + h0.w};
        float4 s1 = {y[4] + h1v.x, y[5] + h1v.y, y[6] + h1v.z, y[7] + h1v.w};
        float* lrow = &ls[wv][fp * 8];
        ((float4*)lrow)[0] = s0;
        ((float4*)lrow)[1] = s1;
    }
    if (lane == 0) lb[wv] = batch[node];
    __syncthreads();
    int f = lane;
    bool same = (lb[0] == lb[1]) && (lb[1] == lb[2]) && (lb[2] == lb[3]);
    if (same) {
        if (wv == 0) {
            float s4 = ls[0][f] + ls[1][f] + ls[2][f] + ls[3][f];
            atomicAdd(&readout[(size_t)lb[0] * HD + f], s4);
        }
    } else {
        atomicAdd(&readout[(size_t)lb[wv] * HD + f], ls[wv][f]);
    }
}

// ---------------- final: out = readout @ post_w + post_b  [G,64]@[64,40] ----------------
__global__ __launch_bounds__(256) void out_gemm(const float* __restrict__ r,
                                                const float* __restrict__ w,
                                                const float* __restrict__ b,
                                                float* __restrict__ out) {
    __shared__ float lw[HD * CO];
    for (int i = threadIdx.x; i < HD * CO; i += 256) lw[i] = w[i];
    __syncthreads();
    int grp = blockIdx.x * 4 + (threadIdx.x >> 6);
    int c = threadIdx.x & 63;
    if (grp >= NG || c >= CO) return;
    const float* rr = r + (size_t)grp * HD;
    float acc = b[c];
#pragma unroll 8
    for (int k = 0; k < HD; k++) acc = fmaf(rr[k], lw[k * CO + c], acc);
    out[(size_t)grp * CO + c] = acc;
}

extern "C" void kernel_launch(void* const* d_in, const int* in_sizes, int n_in,
                              void* d_out, int out_size, void* d_ws, size_t ws_size,
                              hipStream_t stream) {
    const float* x      = (const float*)d_in[0];
    const int*   ei     = (const int*)d_in[1];
    const int*   batch  = (const int*)d_in[2];
    const float* pre_w  = (const float*)d_in[3];
    const float* pre_b  = (const float*)d_in[4];
    const float* c1_w   = (const float*)d_in[5];
    const float* c1_b   = (const float*)d_in[6];
    const float* n1_g   = (const float*)d_in[7];
    const float* n1_b   = (const float*)d_in[8];
    const float* c2_w   = (const float*)d_in[9];
    const float* c2_b   = (const float*)d_in[10];
    const float* n2_g   = (const float*)d_in[11];
    const float* n2_b   = (const float*)d_in[12];
    const float* post_w = (const float*)d_in[13];
    const float* post_b = (const float*)d_in[14];

    const int* src = ei;
    const int* dst = ei + NE;

    char* p = (char*)d_ws;
    int*          ccur    = (int*)p;          p += (size_t)NBUK * 16 * 4;   // padded cursors
    int*          offs    = (int*)p;          p += (size_t)NN * 4;
    int*          degn    = (int*)p;          p += (size_t)NN * 4;
    float*        di      = (float*)p;        p += (size_t)NN * 4;
    float*        weff    = (float*)p;        p += (size_t)FIN * HD * 4;
    float*        beff    = (float*)p;        p += 256;
    unsigned int* tmp     = (unsigned int*)p; p += (size_t)NBUK * BCAP * 4;
    unsigned int* ssrc    = (unsigned int*)p; p += (size_t)NBUK * BCAP * 4;
    float*        h1      = (float*)p;        p += (size_t)NN * HD * 4;
    float*        readout = (float*)p;        p += (size_t)NG * HD * 4;
    __half*       hws     = (__half*)p;       p += (size_t)NN * HD * 2;

    hipMemsetAsync(readout, 0, (size_t)NG * HD * 4, stream);

    // hierarchical CSR build
    init_kernel<<<(NBUK + 255) / 256, 256, 0, stream>>>(ccur);
    scatter_coarse<<<(NE + 255) / 256, 256, 0, stream>>>(src, dst, ccur, tmp);
    bucket_sort<<<NBUK, 256, 0, stream>>>(ccur, tmp, ssrc, offs, degn, di);

    // Folded pre-MLP weights
    weff_kernel<<<33, 256, 0, stream>>>(pre_w, pre_b, c1_w, weff, beff);

    // layer 1
    gemm1_tiled<<<768, 256, 0, stream>>>(x, weff, beff, di, hws);
    gather_ln<<<NN / 4, 256, 0, stream>>>(offs, degn, ssrc, di, hws, c1_b, n1_g, n1_b, h1);

    // layer 2
    conv_gemm_tiled<<<1280, 256, 0, stream>>>(h1, c2_w, di, hws);
    gather_ln_pool<<<NN / 4, 256, 0, stream>>>(offs, degn, ssrc, di, hws, c2_b, n2_g, n2_b, h1, batch, readout);

    out_gemm<<<(NG + 3) / 4, 256, 0, stream>>>(readout, post_w, post_b, (float*)d_out);
}

// Round 10
// 334.454 us; speedup vs baseline: 6.2465x; 1.1337x over previous
//
#include <hip/hip_runtime.h>
#include <hip/hip_fp16.h>

#define NN 100000
#define NE 1600000
#define FIN 128
#define HD 64
#define CO 40
#define NG 2048
#define NBUK 782          // ceil(NN/128)
#define BCAP 3072         // bucket capacity (mean 2046, huge margin)
#define CHUNK 16384       // edges per scatter block
#define NSCAT ((NE + CHUNK - 1) / CHUNK)   // 98

// ---------------- init padded cursors ----------------
__global__ __launch_bounds__(256) void init_kernel(int* __restrict__ ccur) {
    int b = blockIdx.x * 256 + threadIdx.x;
    if (b < NBUK) ccur[b * 16] = b * BCAP;
}

// =====================================================================
// Two-phase binned scatter: per-block LDS histogram over buckets, one
// global reservation atomic per (block,bucket), then writes into the
// block-private range -> every tmp line assembled by ONE workgroup.
// =====================================================================
__global__ __launch_bounds__(256) void scatter_binned(const int* __restrict__ src,
                                                      const int* __restrict__ dst,
                                                      int* __restrict__ ccur,
                                                      unsigned int* __restrict__ tmp) {
    __shared__ int hist[NBUK];
    __shared__ int gbase[NBUK];
    int tid = threadIdx.x;
    int e0 = blockIdx.x * CHUNK;
    int e1 = e0 + CHUNK; if (e1 > NE) e1 = NE;
    for (int i = tid; i < NBUK; i += 256) hist[i] = 0;
    __syncthreads();
    for (int e = e0 + tid; e < e1; e += 256) atomicAdd(&hist[dst[e] >> 7], 1);
    __syncthreads();
    for (int b = tid; b < NBUK; b += 256) {
        int c = hist[b];
        gbase[b] = (c > 0) ? atomicAdd(&ccur[b * 16], c) : 0;
    }
    __syncthreads();
    for (int b = tid; b < NBUK; b += 256) hist[b] = 0;
    __syncthreads();
    for (int e = e0 + tid; e < e1; e += 256) {
        int d = dst[e];
        int s = src[e];
        int b = d >> 7;
        int p = atomicAdd(&hist[b], 1);
        tmp[gbase[b] + p] = ((unsigned int)(d & 127) << 17) | (unsigned int)s;
    }
}

// ---------------- per-bucket counting sort -> dense ssrc + offs/degn/di ----------------
__global__ __launch_bounds__(256) void bucket_sort(const int* __restrict__ ccur,
                                                   const unsigned int* __restrict__ tmp,
                                                   unsigned int* __restrict__ ssrc,
                                                   int* __restrict__ offs,
                                                   int* __restrict__ degn,
                                                   float* __restrict__ di) {
    __shared__ int lh[128];
    __shared__ int ls[128];
    __shared__ int lcur[128];
    __shared__ unsigned int lsorted[BCAP];
    int b = blockIdx.x;
    int tid = threadIdx.x;
    int base = b * BCAP;
    int cnt = ccur[b * 16] - base;
    if (tid < 128) lh[tid] = 0;
    __syncthreads();
    for (int i = tid; i < cnt; i += 256) {
        unsigned int u = tmp[base + i];
        atomicAdd(&lh[(u >> 17) & 127], 1);
    }
    __syncthreads();
    if (tid < 128) ls[tid] = lh[tid];
    __syncthreads();
    for (int off = 1; off < 128; off <<= 1) {
        int v = 0;
        if (tid < 128 && tid >= off) v = ls[tid - off];
        __syncthreads();
        if (tid < 128) ls[tid] += v;
        __syncthreads();
    }
    if (tid < 128) {
        int excl = ls[tid] - lh[tid];
        lcur[tid] = excl;
        int node = b * 128 + tid;
        if (node < NN) {
            offs[node] = base + excl;
            degn[node] = lh[tid];
            di[node] = rsqrtf((float)lh[tid] + 1.0f);
        }
    }
    __syncthreads();
    for (int i = tid; i < cnt; i += 256) {
        unsigned int u = tmp[base + i];
        int dl = (u >> 17) & 127;
        int pos = atomicAdd(&lcur[dl], 1);
        lsorted[pos] = u & 0x1FFFFu;
    }
    __syncthreads();
    for (int i = tid; i < cnt; i += 256) ssrc[base + i] = lsorted[i];
}

// ---------------- W_eff = pre_w @ c1_w ; b_eff = pre_b @ c1_w ----------------
__global__ __launch_bounds__(256) void weff_kernel(const float* __restrict__ pre_w,
                                                   const float* __restrict__ pre_b,
                                                   const float* __restrict__ c1_w,
                                                   float* __restrict__ weff,
                                                   float* __restrict__ beff) {
    if (blockIdx.x < 32) {
        int o = blockIdx.x * 256 + threadIdx.x;  // [0, 8192)
        int r = o >> 6, c = o & 63;
        float acc = 0.0f;
#pragma unroll 8
        for (int k = 0; k < HD; k++) acc = fmaf(pre_w[r * HD + k], c1_w[k * HD + c], acc);
        weff[o] = acc;
    } else {
        int c = threadIdx.x;
        if (c < HD) {
            float acc = 0.0f;
#pragma unroll 8
            for (int k = 0; k < HD; k++) acc = fmaf(pre_b[k], c1_w[k * HD + c], acc);
            beff[c] = acc;
        }
    }
}

// =====================================================================
// Tiled GEMM 1: hws = half((x @ W_eff + b_eff) * di)   [N,128]@[128,64]
// =====================================================================
__global__ __launch_bounds__(256) void gemm1_tiled(const float* __restrict__ x,
                                                   const float* __restrict__ w,
                                                   const float* __restrict__ b,
                                                   const float* __restrict__ di,
                                                   __half* __restrict__ hws) {
    __shared__ float wS[FIN * HD];   // 32 KB
    __shared__ float xS[64 * 64];    // 16 KB (one K-half)
    int tid = threadIdx.x;
    for (int i = tid; i < FIN * HD; i += 256) wS[i] = w[i];
    int tn = tid & 15, tf = tid >> 4;
    int f0 = tf * 4;
    float4 bv = ((const float4*)b)[tf];
    int ntiles = (NN + 63) >> 6;
    for (int t = blockIdx.x; t < ntiles; t += gridDim.x) {
        int nb = t << 6;
        float acc[4][4];
#pragma unroll
        for (int i = 0; i < 4; i++)
#pragma unroll
            for (int j = 0; j < 4; j++) acc[i][j] = 0.0f;
        for (int kh = 0; kh < 2; kh++) {
            __syncthreads();
            {
                int n_l = tid >> 4;
                int k4l = tid & 15;
                for (int r = 0; r < 4; r++) {
                    int n = n_l + r * 16;
                    int row = nb + n;
                    float4 v = make_float4(0.f, 0.f, 0.f, 0.f);
                    if (row < NN) v = ((const float4*)(x + (size_t)row * FIN))[kh * 16 + k4l];
                    int g = n >> 2, nl2 = n & 3;
                    const float* vp = (const float*)&v;
#pragma unroll
                    for (int j = 0; j < 4; j++) {
                        int k = k4l * 4 + j;
                        int gp = g ^ (k & 15);
                        xS[k * 64 + gp * 4 + nl2] = vp[j];
                    }
                }
            }
            __syncthreads();
#pragma unroll 4
            for (int kl = 0; kl < 64; kl++) {
                int gp = tn ^ (kl & 15);
                float4 xv = *(const float4*)&xS[kl * 64 + gp * 4];
                float4 wv = *(const float4*)&wS[(kh * 64 + kl) * 64 + f0];
                acc[0][0] = fmaf(xv.x, wv.x, acc[0][0]); acc[0][1] = fmaf(xv.x, wv.y, acc[0][1]);
                acc[0][2] = fmaf(xv.x, wv.z, acc[0][2]); acc[0][3] = fmaf(xv.x, wv.w, acc[0][3]);
                acc[1][0] = fmaf(xv.y, wv.x, acc[1][0]); acc[1][1] = fmaf(xv.y, wv.y, acc[1][1]);
                acc[1][2] = fmaf(xv.y, wv.z, acc[1][2]); acc[1][3] = fmaf(xv.y, wv.w, acc[1][3]);
                acc[2][0] = fmaf(xv.z, wv.x, acc[2][0]); acc[2][1] = fmaf(xv.z, wv.y, acc[2][1]);
                acc[2][2] = fmaf(xv.z, wv.z, acc[2][2]); acc[2][3] = fmaf(xv.z, wv.w, acc[2][3]);
                acc[3][0] = fmaf(xv.w, wv.x, acc[3][0]); acc[3][1] = fmaf(xv.w, wv.y, acc[3][1]);
                acc[3][2] = fmaf(xv.w, wv.z, acc[3][2]); acc[3][3] = fmaf(xv.w, wv.w, acc[3][3]);
            }
        }
        int n0 = nb + tn * 4;
#pragma unroll
        for (int i = 0; i < 4; i++) {
            int n = n0 + i;
            if (n < NN) {
                float dn = di[n];
                __half2 p0 = __floats2half2_rn((acc[i][0] + bv.x) * dn, (acc[i][1] + bv.y) * dn);
                __half2 p1 = __floats2half2_rn((acc[i][2] + bv.z) * dn, (acc[i][3] + bv.w) * dn);
                __half2* o = (__half2*)(hws + (size_t)n * HD + f0);
                o[0] = p0; o[1] = p1;
            }
        }
    }
}

// =====================================================================
// Tiled GEMM 2: hws = half((h1 @ c2_w) * di)   [N,64]@[64,64], h1 fp16
// =====================================================================
__global__ __launch_bounds__(256) void conv_gemm_tiled(const __half* __restrict__ hin,
                                                       const float* __restrict__ w,
                                                       const float* __restrict__ di,
                                                       __half* __restrict__ hws) {
    __shared__ float wS[HD * HD];   // 16 KB
    __shared__ float xS[64 * HD];   // 16 KB
    int tid = threadIdx.x;
    for (int i = tid; i < HD * HD; i += 256) wS[i] = w[i];
    int tn = tid & 15, tf = tid >> 4;
    int f0 = tf * 4;
    int ntiles = (NN + 63) >> 6;
    for (int t = blockIdx.x; t < ntiles; t += gridDim.x) {
        int nb = t << 6;
        __syncthreads();
        {   // stage fp16 rows: 16B = 8 halves per thread-load
            int n_l = tid >> 3;   // 0..31
            int k8 = tid & 7;     // 0..7 (8 float4 per 128B row)
            union U { float4 f4; __half2 h2[4]; } u;
            for (int r = 0; r < 2; r++) {
                int n = n_l + r * 32;
                int row = nb + n;
                u.f4 = make_float4(0.f, 0.f, 0.f, 0.f);
                if (row < NN) u.f4 = ((const float4*)(hin + (size_t)row * HD))[k8];
                int g = n >> 2, nl2 = n & 3;
#pragma unroll
                for (int j = 0; j < 4; j++) {
                    float2 p = __half22float2(u.h2[j]);
                    int k = k8 * 8 + 2 * j;
                    int gp = g ^ (k & 15);
                    xS[k * 64 + gp * 4 + nl2] = p.x;
                    int k2 = k + 1;
                    int gp2 = g ^ (k2 & 15);
                    xS[k2 * 64 + gp2 * 4 + nl2] = p.y;
                }
            }
        }
        __syncthreads();
        float acc[4][4];
#pragma unroll
        for (int i = 0; i < 4; i++)
#pragma unroll
            for (int j = 0; j < 4; j++) acc[i][j] = 0.0f;
#pragma unroll 4
        for (int k = 0; k < HD; k++) {
            int gp = tn ^ (k & 15);
            float4 xv = *(const float4*)&xS[k * 64 + gp * 4];
            float4 wv = *(const float4*)&wS[k * 64 + f0];
            acc[0][0] = fmaf(xv.x, wv.x, acc[0][0]); acc[0][1] = fmaf(xv.x, wv.y, acc[0][1]);
            acc[0][2] = fmaf(xv.x, wv.z, acc[0][2]); acc[0][3] = fmaf(xv.x, wv.w, acc[0][3]);
            acc[1][0] = fmaf(xv.y, wv.x, acc[1][0]); acc[1][1] = fmaf(xv.y, wv.y, acc[1][1]);
            acc[1][2] = fmaf(xv.y, wv.z, acc[1][2]); acc[1][3] = fmaf(xv.y, wv.w, acc[1][3]);
            acc[2][0] = fmaf(xv.z, wv.x, acc[2][0]); acc[2][1] = fmaf(xv.z, wv.y, acc[2][1]);
            acc[2][2] = fmaf(xv.z, wv.z, acc[2][2]); acc[2][3] = fmaf(xv.z, wv.w, acc[2][3]);
            acc[3][0] = fmaf(xv.w, wv.x, acc[3][0]); acc[3][1] = fmaf(xv.w, wv.y, acc[3][1]);
            acc[3][2] = fmaf(xv.w, wv.z, acc[3][2]); acc[3][3] = fmaf(xv.w, wv.w, acc[3][3]);
        }
        int n0 = nb + tn * 4;
#pragma unroll
        for (int i = 0; i < 4; i++) {
            int n = n0 + i;
            if (n < NN) {
                float dn = di[n];
                __half2 p0 = __floats2half2_rn(acc[i][0] * dn, acc[i][1] * dn);
                __half2 p1 = __floats2half2_rn(acc[i][2] * dn, acc[i][3] * dn);
                __half2* o = (__half2*)(hws + (size_t)n * HD + f0);
                o[0] = p0; o[1] = p1;
            }
        }
    }
}

// =====================================================================
// Gather core (fp16 rows): wave per node, 8 lanes/row (16B each), 8 rows
// per shuffle round. All __shfl executed by all 64 lanes (bpermute rule).
// =====================================================================
__device__ __forceinline__ void gather_half(const int* __restrict__ offs,
                                            const int* __restrict__ degn,
                                            const unsigned int* __restrict__ ssrc,
                                            const __half* __restrict__ hws,
                                            int node, int lane, int fp, int rsub,
                                            float acc[8]) {
    int beg = offs[node];
    int end = beg + degn[node];
    union U { float4 f4; __half2 h2[4]; } u;
#pragma unroll
    for (int t = 0; t < 8; t++) acc[t] = 0.0f;
    if (rsub == 0) {
        u.f4 = ((const float4*)(hws + (size_t)node * HD))[fp];
#pragma unroll
        for (int t = 0; t < 4; t++) {
            float2 p = __half22float2(u.h2[t]);
            acc[2 * t] += p.x; acc[2 * t + 1] += p.y;
        }
    }
    int i = beg;
    while (i < end) {
        int cnt = end - i;
        if (cnt > 64) cnt = 64;
        int sl = (lane < cnt) ? (int)ssrc[i + lane] : 0;
        int j = 0;
        for (; j + 8 <= cnt; j += 8) {
            int s = __shfl(sl, j + rsub, 64);
            u.f4 = ((const float4*)(hws + (size_t)s * HD))[fp];
#pragma unroll
            for (int t = 0; t < 4; t++) {
                float2 p = __half22float2(u.h2[t]);
                acc[2 * t] += p.x; acc[2 * t + 1] += p.y;
            }
        }
        if (j < cnt) {
            int jr = j + rsub;
            int s = __shfl(sl, (jr < cnt) ? jr : 0, 64);
            if (jr < cnt) {
                u.f4 = ((const float4*)(hws + (size_t)s * HD))[fp];
#pragma unroll
                for (int t = 0; t < 4; t++) {
                    float2 p = __half22float2(u.h2[t]);
                    acc[2 * t] += p.x; acc[2 * t + 1] += p.y;
                }
            }
        }
        i += cnt;
    }
#pragma unroll
    for (int t = 0; t < 8; t++) {
        acc[t] += __shfl_xor(acc[t], 8, 64);
        acc[t] += __shfl_xor(acc[t], 16, 64);
        acc[t] += __shfl_xor(acc[t], 32, 64);
    }
}

// LN over the 8-features-per-lane layout; returns relu'd y[8].
__device__ __forceinline__ void ln8(float v[8], int fp,
                                    const float* __restrict__ g,
                                    const float* __restrict__ bb,
                                    float y[8]) {
    float su = 0.0f;
#pragma unroll
    for (int t = 0; t < 8; t++) su += v[t];
    su += __shfl_xor(su, 1, 64); su += __shfl_xor(su, 2, 64); su += __shfl_xor(su, 4, 64);
    float mu = su * (1.0f / HD);
    float q = 0.0f;
#pragma unroll
    for (int t = 0; t < 8; t++) { float d = v[t] - mu; q += d * d; }
    q += __shfl_xor(q, 1, 64); q += __shfl_xor(q, 2, 64); q += __shfl_xor(q, 4, 64);
    float rstd = rsqrtf(q * (1.0f / HD) + 1e-5f);
    float4 ga = ((const float4*)g)[fp * 2], gb = ((const float4*)g)[fp * 2 + 1];
    float4 ba = ((const float4*)bb)[fp * 2], bc = ((const float4*)bb)[fp * 2 + 1];
    float gv[8] = {ga.x, ga.y, ga.z, ga.w, gb.x, gb.y, gb.z, gb.w};
    float bv[8] = {ba.x, ba.y, ba.z, ba.w, bc.x, bc.y, bc.z, bc.w};
#pragma unroll
    for (int t = 0; t < 8; t++) y[t] = fmaxf((v[t] - mu) * rstd * gv[t] + bv[t], 0.0f);
}

// ---------------- layer-1 gather + bias + LN + ReLU -> h1 (fp16) ----------------
__global__ __launch_bounds__(256) void gather_ln(const int* __restrict__ offs,
                                                 const int* __restrict__ degn,
                                                 const unsigned int* __restrict__ ssrc,
                                                 const float* __restrict__ di,
                                                 const __half* __restrict__ hws,
                                                 const float* __restrict__ cb,
                                                 const float* __restrict__ g,
                                                 const float* __restrict__ bb,
                                                 __half* __restrict__ out) {
    int wv = threadIdx.x >> 6;
    int lane = threadIdx.x & 63;
    int fp = lane & 7, rsub = lane >> 3;
    int node = blockIdx.x * 4 + wv;      // NN % 4 == 0
    float acc[8];
    gather_half(offs, degn, ssrc, hws, node, lane, fp, rsub, acc);
    float dn = di[node];
    float4 ca = ((const float4*)cb)[fp * 2], cc = ((const float4*)cb)[fp * 2 + 1];
    float cv[8] = {ca.x, ca.y, ca.z, ca.w, cc.x, cc.y, cc.z, cc.w};
    float v[8], y[8];
#pragma unroll
    for (int t = 0; t < 8; t++) v[t] = acc[t] * dn + cv[t];
    ln8(v, fp, g, bb, y);
    if (rsub == 0) {
        union U { float4 f4; __half2 h2[4]; } u;
#pragma unroll
        for (int t = 0; t < 4; t++) u.h2[t] = __floats2half2_rn(y[2 * t], y[2 * t + 1]);
        ((float4*)(out + (size_t)node * HD))[fp] = u.f4;
    }
}

// ---------------- layer-2 gather + LN + ReLU + skip + pooled scatter ----------------
__global__ __launch_bounds__(256) void gather_ln_pool(const int* __restrict__ offs,
                                                      const int* __restrict__ degn,
                                                      const unsigned int* __restrict__ ssrc,
                                                      const float* __restrict__ di,
                                                      const __half* __restrict__ hws,
                                                      const float* __restrict__ cb,
                                                      const float* __restrict__ g,
                                                      const float* __restrict__ bb,
                                                      const __half* __restrict__ h1,
                                                      const int* __restrict__ batch,
                                                      float* __restrict__ readout) {
    __shared__ float ls[4][HD];
    __shared__ int lb[4];
    int wv = threadIdx.x >> 6;
    int lane = threadIdx.x & 63;
    int fp = lane & 7, rsub = lane >> 3;
    int node = blockIdx.x * 4 + wv;
    float acc[8];
    gather_half(offs, degn, ssrc, hws, node, lane, fp, rsub, acc);
    float dn = di[node];
    float4 ca = ((const float4*)cb)[fp * 2], cc = ((const float4*)cb)[fp * 2 + 1];
    float cv[8] = {ca.x, ca.y, ca.z, ca.w, cc.x, cc.y, cc.z, cc.w};
    float v[8], y[8];
#pragma unroll
    for (int t = 0; t < 8; t++) v[t] = acc[t] * dn + cv[t];
    ln8(v, fp, g, bb, y);
    if (rsub == 0) {
        union U { float4 f4; __half2 h2[4]; } u;
        u.f4 = ((const float4*)(h1 + (size_t)node * HD))[fp];
        float* lrow = &ls[wv][fp * 8];
#pragma unroll
        for (int t = 0; t < 4; t++) {
            float2 p = __half22float2(u.h2[t]);
            lrow[2 * t] = y[2 * t] + p.x;
            lrow[2 * t + 1] = y[2 * t + 1] + p.y;
        }
    }
    if (lane == 0) lb[wv] = batch[node];
    __syncthreads();
    int f = lane;
    bool same = (lb[0] == lb[1]) && (lb[1] == lb[2]) && (lb[2] == lb[3]);
    if (same) {
        if (wv == 0) {
            float s4 = ls[0][f] + ls[1][f] + ls[2][f] + ls[3][f];
            atomicAdd(&readout[(size_t)lb[0] * HD + f], s4);
        }
    } else {
        atomicAdd(&readout[(size_t)lb[wv] * HD + f], ls[wv][f]);
    }
}

// ---------------- final: out = readout @ post_w + post_b  [G,64]@[64,40] ----------------
__global__ __launch_bounds__(256) void out_gemm(const float* __restrict__ r,
                                                const float* __restrict__ w,
                                                const float* __restrict__ b,
                                                float* __restrict__ out) {
    __shared__ float lw[HD * CO];
    for (int i = threadIdx.x; i < HD * CO; i += 256) lw[i] = w[i];
    __syncthreads();
    int grp = blockIdx.x * 4 + (threadIdx.x >> 6);
    int c = threadIdx.x & 63;
    if (grp >= NG || c >= CO) return;
    const float* rr = r + (size_t)grp * HD;
    float acc = b[c];
#pragma unroll 8
    for (int k = 0; k < HD; k++) acc = fmaf(rr[k], lw[k * CO + c], acc);
    out[(size_t)grp * CO + c] = acc;
}

extern "C" void kernel_launch(void* const* d_in, const int* in_sizes, int n_in,
                              void* d_out, int out_size, void* d_ws, size_t ws_size,
                              hipStream_t stream) {
    const float* x      = (const float*)d_in[0];
    const int*   ei     = (const int*)d_in[1];
    const int*   batch  = (const int*)d_in[2];
    const float* pre_w  = (const float*)d_in[3];
    const float* pre_b  = (const float*)d_in[4];
    const float* c1_w   = (const float*)d_in[5];
    const float* c1_b   = (const float*)d_in[6];
    const float* n1_g   = (const float*)d_in[7];
    const float* n1_b   = (const float*)d_in[8];
    const float* c2_w   = (const float*)d_in[9];
    const float* c2_b   = (const float*)d_in[10];
    const float* n2_g   = (const float*)d_in[11];
    const float* n2_b   = (const float*)d_in[12];
    const float* post_w = (const float*)d_in[13];
    const float* post_b = (const float*)d_in[14];

    const int* src = ei;
    const int* dst = ei + NE;

    char* p = (char*)d_ws;
    int*          ccur    = (int*)p;          p += (size_t)NBUK * 16 * 4;
    int*          offs    = (int*)p;          p += (size_t)NN * 4;
    int*          degn    = (int*)p;          p += (size_t)NN * 4;
    float*        di      = (float*)p;        p += (size_t)NN * 4;
    float*        weff    = (float*)p;        p += (size_t)FIN * HD * 4;
    float*        beff    = (float*)p;        p += 256;
    unsigned int* tmp     = (unsigned int*)p; p += (size_t)NBUK * BCAP * 4;
    unsigned int* ssrc    = (unsigned int*)p; p += (size_t)NBUK * BCAP * 4;
    float*        readout = (float*)p;        p += (size_t)NG * HD * 4;
    __half*       hws     = (__half*)p;       p += (size_t)NN * HD * 2;
    __half*       h1      = (__half*)p;       p += (size_t)NN * HD * 2;

    hipMemsetAsync(readout, 0, (size_t)NG * HD * 4, stream);

    // hierarchical CSR build (binned scatter -> per-bucket counting sort)
    init_kernel<<<(NBUK + 255) / 256, 256, 0, stream>>>(ccur);
    scatter_binned<<<NSCAT, 256, 0, stream>>>(src, dst, ccur, tmp);
    bucket_sort<<<NBUK, 256, 0, stream>>>(ccur, tmp, ssrc, offs, degn, di);

    // Folded pre-MLP weights
    weff_kernel<<<33, 256, 0, stream>>>(pre_w, pre_b, c1_w, weff, beff);

    // layer 1
    gemm1_tiled<<<768, 256, 0, stream>>>(x, weff, beff, di, hws);
    gather_ln<<<NN / 4, 256, 0, stream>>>(offs, degn, ssrc, di, hws, c1_b, n1_g, n1_b, h1);

    // layer 2
    conv_gemm_tiled<<<1280, 256, 0, stream>>>(h1, c2_w, di, hws);
    gather_ln_pool<<<NN / 4, 256, 0, stream>>>(offs, degn, ssrc, di, hws, c2_b, n2_g, n2_b, h1, batch, readout);

    out_gemm<<<(NG + 3) / 4, 256, 0, stream>>>(readout, post_w, post_b, (float*)d_out);
}

// Round 11
// 323.927 us; speedup vs baseline: 6.4495x; 1.0325x over previous
//
#include <hip/hip_runtime.h>
#include <hip/hip_fp16.h>

#define NN 100000
#define NE 1600000
#define FIN 128
#define HD 64
#define CO 40
#define NG 2048
#define NBUK 782          // ceil(NN/128)
#define BCAP 3072         // bucket capacity (mean 2046, huge margin)
#define CHUNK 4096        // edges per scatter block
#define NSCAT ((NE + CHUNK - 1) / CHUNK)   // 391

// ---------------- init padded cursors ----------------
__global__ __launch_bounds__(256) void init_kernel(int* __restrict__ ccur) {
    int b = blockIdx.x * 256 + threadIdx.x;
    if (b < NBUK) ccur[b * 16] = b * BCAP;
}

// =====================================================================
// Two-phase binned scatter: per-block LDS histogram over buckets, one
// global reservation atomic per (block,bucket), then writes into the
// block-private range -> every tmp line assembled by ONE workgroup.
// =====================================================================
__global__ __launch_bounds__(256) void scatter_binned(const int* __restrict__ src,
                                                      const int* __restrict__ dst,
                                                      int* __restrict__ ccur,
                                                      unsigned int* __restrict__ tmp) {
    __shared__ int hist[NBUK];
    __shared__ int gbase[NBUK];
    int tid = threadIdx.x;
    int e0 = blockIdx.x * CHUNK;
    int e1 = e0 + CHUNK; if (e1 > NE) e1 = NE;
    for (int i = tid; i < NBUK; i += 256) hist[i] = 0;
    __syncthreads();
    for (int e = e0 + tid; e < e1; e += 256) atomicAdd(&hist[dst[e] >> 7], 1);
    __syncthreads();
    for (int b = tid; b < NBUK; b += 256) {
        int c = hist[b];
        gbase[b] = (c > 0) ? atomicAdd(&ccur[b * 16], c) : 0;
    }
    __syncthreads();
    for (int b = tid; b < NBUK; b += 256) hist[b] = 0;
    __syncthreads();
    for (int e = e0 + tid; e < e1; e += 256) {
        int d = dst[e];
        int s = src[e];
        int b = d >> 7;
        int p = atomicAdd(&hist[b], 1);
        tmp[gbase[b] + p] = ((unsigned int)(d & 127) << 17) | (unsigned int)s;
    }
}

// ---------------- per-bucket counting sort -> dense ssrc + offs/degn/di ----------------
__global__ __launch_bounds__(256) void bucket_sort(const int* __restrict__ ccur,
                                                   const unsigned int* __restrict__ tmp,
                                                   unsigned int* __restrict__ ssrc,
                                                   int* __restrict__ offs,
                                                   int* __restrict__ degn,
                                                   float* __restrict__ di) {
    __shared__ int lh[128];
    __shared__ int ls[128];
    __shared__ int lcur[128];
    __shared__ unsigned int lsorted[BCAP];
    int b = blockIdx.x;
    int tid = threadIdx.x;
    int base = b * BCAP;
    int cnt = ccur[b * 16] - base;
    if (tid < 128) lh[tid] = 0;
    __syncthreads();
    for (int i = tid; i < cnt; i += 256) {
        unsigned int u = tmp[base + i];
        atomicAdd(&lh[(u >> 17) & 127], 1);
    }
    __syncthreads();
    if (tid < 128) ls[tid] = lh[tid];
    __syncthreads();
    for (int off = 1; off < 128; off <<= 1) {
        int v = 0;
        if (tid < 128 && tid >= off) v = ls[tid - off];
        __syncthreads();
        if (tid < 128) ls[tid] += v;
        __syncthreads();
    }
    if (tid < 128) {
        int excl = ls[tid] - lh[tid];
        lcur[tid] = excl;
        int node = b * 128 + tid;
        if (node < NN) {
            offs[node] = base + excl;
            degn[node] = lh[tid];
            di[node] = rsqrtf((float)lh[tid] + 1.0f);
        }
    }
    __syncthreads();
    for (int i = tid; i < cnt; i += 256) {
        unsigned int u = tmp[base + i];
        int dl = (u >> 17) & 127;
        int pos = atomicAdd(&lcur[dl], 1);
        lsorted[pos] = u & 0x1FFFFu;
    }
    __syncthreads();
    for (int i = tid; i < cnt; i += 256) ssrc[base + i] = lsorted[i];
}

// ---------------- W_eff = pre_w @ c1_w ; b_eff = pre_b @ c1_w ----------------
__global__ __launch_bounds__(256) void weff_kernel(const float* __restrict__ pre_w,
                                                   const float* __restrict__ pre_b,
                                                   const float* __restrict__ c1_w,
                                                   float* __restrict__ weff,
                                                   float* __restrict__ beff) {
    if (blockIdx.x < 32) {
        int o = blockIdx.x * 256 + threadIdx.x;  // [0, 8192)
        int r = o >> 6, c = o & 63;
        float acc = 0.0f;
#pragma unroll 8
        for (int k = 0; k < HD; k++) acc = fmaf(pre_w[r * HD + k], c1_w[k * HD + c], acc);
        weff[o] = acc;
    } else {
        int c = threadIdx.x;
        if (c < HD) {
            float acc = 0.0f;
#pragma unroll 8
            for (int k = 0; k < HD; k++) acc = fmaf(pre_b[k], c1_w[k * HD + c], acc);
            beff[c] = acc;
        }
    }
}

// =====================================================================
// Tiled GEMM 1: hws = half((x @ W_eff + b_eff) * di)   [N,128]@[128,64]
// =====================================================================
__global__ __launch_bounds__(256) void gemm1_tiled(const float* __restrict__ x,
                                                   const float* __restrict__ w,
                                                   const float* __restrict__ b,
                                                   const float* __restrict__ di,
                                                   __half* __restrict__ hws) {
    __shared__ float wS[FIN * HD];   // 32 KB
    __shared__ float xS[64 * 64];    // 16 KB (one K-half)
    int tid = threadIdx.x;
    for (int i = tid; i < FIN * HD; i += 256) wS[i] = w[i];
    int tn = tid & 15, tf = tid >> 4;
    int f0 = tf * 4;
    float4 bv = ((const float4*)b)[tf];
    int ntiles = (NN + 63) >> 6;
    for (int t = blockIdx.x; t < ntiles; t += gridDim.x) {
        int nb = t << 6;
        float acc[4][4];
#pragma unroll
        for (int i = 0; i < 4; i++)
#pragma unroll
            for (int j = 0; j < 4; j++) acc[i][j] = 0.0f;
        for (int kh = 0; kh < 2; kh++) {
            __syncthreads();
            {
                int n_l = tid >> 4;
                int k4l = tid & 15;
                for (int r = 0; r < 4; r++) {
                    int n = n_l + r * 16;
                    int row = nb + n;
                    float4 v = make_float4(0.f, 0.f, 0.f, 0.f);
                    if (row < NN) v = ((const float4*)(x + (size_t)row * FIN))[kh * 16 + k4l];
                    int g = n >> 2, nl2 = n & 3;
                    const float* vp = (const float*)&v;
#pragma unroll
                    for (int j = 0; j < 4; j++) {
                        int k = k4l * 4 + j;
                        int gp = g ^ (k & 15);
                        xS[k * 64 + gp * 4 + nl2] = vp[j];
                    }
                }
            }
            __syncthreads();
#pragma unroll 4
            for (int kl = 0; kl < 64; kl++) {
                int gp = tn ^ (kl & 15);
                float4 xv = *(const float4*)&xS[kl * 64 + gp * 4];
                float4 wv = *(const float4*)&wS[(kh * 64 + kl) * 64 + f0];
                acc[0][0] = fmaf(xv.x, wv.x, acc[0][0]); acc[0][1] = fmaf(xv.x, wv.y, acc[0][1]);
                acc[0][2] = fmaf(xv.x, wv.z, acc[0][2]); acc[0][3] = fmaf(xv.x, wv.w, acc[0][3]);
                acc[1][0] = fmaf(xv.y, wv.x, acc[1][0]); acc[1][1] = fmaf(xv.y, wv.y, acc[1][1]);
                acc[1][2] = fmaf(xv.y, wv.z, acc[1][2]); acc[1][3] = fmaf(xv.y, wv.w, acc[1][3]);
                acc[2][0] = fmaf(xv.z, wv.x, acc[2][0]); acc[2][1] = fmaf(xv.z, wv.y, acc[2][1]);
                acc[2][2] = fmaf(xv.z, wv.z, acc[2][2]); acc[2][3] = fmaf(xv.z, wv.w, acc[2][3]);
                acc[3][0] = fmaf(xv.w, wv.x, acc[3][0]); acc[3][1] = fmaf(xv.w, wv.y, acc[3][1]);
                acc[3][2] = fmaf(xv.w, wv.z, acc[3][2]); acc[3][3] = fmaf(xv.w, wv.w, acc[3][3]);
            }
        }
        int n0 = nb + tn * 4;
#pragma unroll
        for (int i = 0; i < 4; i++) {
            int n = n0 + i;
            if (n < NN) {
                float dn = di[n];
                __half2 p0 = __floats2half2_rn((acc[i][0] + bv.x) * dn, (acc[i][1] + bv.y) * dn);
                __half2 p1 = __floats2half2_rn((acc[i][2] + bv.z) * dn, (acc[i][3] + bv.w) * dn);
                __half2* o = (__half2*)(hws + (size_t)n * HD + f0);
                o[0] = p0; o[1] = p1;
            }
        }
    }
}

// =====================================================================
// Tiled GEMM 2: hws = half((h1 @ c2_w) * di)   [N,64]@[64,64], h1 fp16
// =====================================================================
__global__ __launch_bounds__(256) void conv_gemm_tiled(const __half* __restrict__ hin,
                                                       const float* __restrict__ w,
                                                       const float* __restrict__ di,
                                                       __half* __restrict__ hws) {
    __shared__ float wS[HD * HD];   // 16 KB
    __shared__ float xS[64 * HD];   // 16 KB
    int tid = threadIdx.x;
    for (int i = tid; i < HD * HD; i += 256) wS[i] = w[i];
    int tn = tid & 15, tf = tid >> 4;
    int f0 = tf * 4;
    int ntiles = (NN + 63) >> 6;
    for (int t = blockIdx.x; t < ntiles; t += gridDim.x) {
        int nb = t << 6;
        __syncthreads();
        {   // stage fp16 rows: 16B = 8 halves per thread-load
            int n_l = tid >> 3;   // 0..31
            int k8 = tid & 7;     // 0..7
            union U { float4 f4; __half2 h2[4]; } u;
            for (int r = 0; r < 2; r++) {
                int n = n_l + r * 32;
                int row = nb + n;
                u.f4 = make_float4(0.f, 0.f, 0.f, 0.f);
                if (row < NN) u.f4 = ((const float4*)(hin + (size_t)row * HD))[k8];
                int g = n >> 2, nl2 = n & 3;
#pragma unroll
                for (int j = 0; j < 4; j++) {
                    float2 p = __half22float2(u.h2[j]);
                    int k = k8 * 8 + 2 * j;
                    int gp = g ^ (k & 15);
                    xS[k * 64 + gp * 4 + nl2] = p.x;
                    int k2 = k + 1;
                    int gp2 = g ^ (k2 & 15);
                    xS[k2 * 64 + gp2 * 4 + nl2] = p.y;
                }
            }
        }
        __syncthreads();
        float acc[4][4];
#pragma unroll
        for (int i = 0; i < 4; i++)
#pragma unroll
            for (int j = 0; j < 4; j++) acc[i][j] = 0.0f;
#pragma unroll 4
        for (int k = 0; k < HD; k++) {
            int gp = tn ^ (k & 15);
            float4 xv = *(const float4*)&xS[k * 64 + gp * 4];
            float4 wv = *(const float4*)&wS[k * 64 + f0];
            acc[0][0] = fmaf(xv.x, wv.x, acc[0][0]); acc[0][1] = fmaf(xv.x, wv.y, acc[0][1]);
            acc[0][2] = fmaf(xv.x, wv.z, acc[0][2]); acc[0][3] = fmaf(xv.x, wv.w, acc[0][3]);
            acc[1][0] = fmaf(xv.y, wv.x, acc[1][0]); acc[1][1] = fmaf(xv.y, wv.y, acc[1][1]);
            acc[1][2] = fmaf(xv.y, wv.z, acc[1][2]); acc[1][3] = fmaf(xv.y, wv.w, acc[1][3]);
            acc[2][0] = fmaf(xv.z, wv.x, acc[2][0]); acc[2][1] = fmaf(xv.z, wv.y, acc[2][1]);
            acc[2][2] = fmaf(xv.z, wv.z, acc[2][2]); acc[2][3] = fmaf(xv.z, wv.w, acc[2][3]);
            acc[3][0] = fmaf(xv.w, wv.x, acc[3][0]); acc[3][1] = fmaf(xv.w, wv.y, acc[3][1]);
            acc[3][2] = fmaf(xv.w, wv.z, acc[3][2]); acc[3][3] = fmaf(xv.w, wv.w, acc[3][3]);
        }
        int n0 = nb + tn * 4;
#pragma unroll
        for (int i = 0; i < 4; i++) {
            int n = n0 + i;
            if (n < NN) {
                float dn = di[n];
                __half2 p0 = __floats2half2_rn(acc[i][0] * dn, acc[i][1] * dn);
                __half2 p1 = __floats2half2_rn(acc[i][2] * dn, acc[i][3] * dn);
                __half2* o = (__half2*)(hws + (size_t)n * HD + f0);
                o[0] = p0; o[1] = p1;
            }
        }
    }
}

// =====================================================================
// Gather core (fp16 rows): wave per node, 8 lanes/row (16B each), 8 rows
// per shuffle round. Accumulation in packed fp16 (v_pk_add_f16): per-lane
// partial sums are short (~deg/8 ~2-3 rows), so fp16 rounding is
// negligible; converted to f32 before the cross-lane reduce.
// All __shfl executed by all 64 lanes (bpermute rule).
// =====================================================================
__device__ __forceinline__ void gather_half(const int* __restrict__ offs,
                                            const int* __restrict__ degn,
                                            const unsigned int* __restrict__ ssrc,
                                            const __half* __restrict__ hws,
                                            int node, int lane, int fp, int rsub,
                                            float acc[8]) {
    int beg = offs[node];
    int end = beg + degn[node];
    union U { float4 f4; __half2 h2[4]; } u;
    __half2 hacc[4];
#pragma unroll
    for (int t = 0; t < 4; t++) hacc[t] = __floats2half2_rn(0.0f, 0.0f);
    if (rsub == 0) {  // self-loop term counted once
        u.f4 = ((const float4*)(hws + (size_t)node * HD))[fp];
#pragma unroll
        for (int t = 0; t < 4; t++) hacc[t] = __hadd2(hacc[t], u.h2[t]);
    }
    int i = beg;
    while (i < end) {
        int cnt = end - i;
        if (cnt > 64) cnt = 64;
        int sl = (lane < cnt) ? (int)ssrc[i + lane] : 0;
        int j = 0;
        for (; j + 8 <= cnt; j += 8) {
            int s = __shfl(sl, j + rsub, 64);   // non-divergent
            u.f4 = ((const float4*)(hws + (size_t)s * HD))[fp];
#pragma unroll
            for (int t = 0; t < 4; t++) hacc[t] = __hadd2(hacc[t], u.h2[t]);
        }
        if (j < cnt) {  // tail 1..7 rows
            int jr = j + rsub;
            int s = __shfl(sl, (jr < cnt) ? jr : 0, 64);  // all lanes execute
            if (jr < cnt) {
                u.f4 = ((const float4*)(hws + (size_t)s * HD))[fp];
#pragma unroll
                for (int t = 0; t < 4; t++) hacc[t] = __hadd2(hacc[t], u.h2[t]);
            }
        }
        i += cnt;
    }
#pragma unroll
    for (int t = 0; t < 4; t++) {
        float2 p = __half22float2(hacc[t]);
        acc[2 * t] = p.x; acc[2 * t + 1] = p.y;
    }
#pragma unroll
    for (int t = 0; t < 8; t++) {
        acc[t] += __shfl_xor(acc[t], 8, 64);
        acc[t] += __shfl_xor(acc[t], 16, 64);
        acc[t] += __shfl_xor(acc[t], 32, 64);
    }
}

// LN over the 8-features-per-lane layout; returns relu'd y[8].
__device__ __forceinline__ void ln8(float v[8], int fp,
                                    const float* __restrict__ g,
                                    const float* __restrict__ bb,
                                    float y[8]) {
    float su = 0.0f;
#pragma unroll
    for (int t = 0; t < 8; t++) su += v[t];
    su += __shfl_xor(su, 1, 64); su += __shfl_xor(su, 2, 64); su += __shfl_xor(su, 4, 64);
    float mu = su * (1.0f / HD);
    float q = 0.0f;
#pragma unroll
    for (int t = 0; t < 8; t++) { float d = v[t] - mu; q += d * d; }
    q += __shfl_xor(q, 1, 64); q += __shfl_xor(q, 2, 64); q += __shfl_xor(q, 4, 64);
    float rstd = rsqrtf(q * (1.0f / HD) + 1e-5f);
    float4 ga = ((const float4*)g)[fp * 2], gb = ((const float4*)g)[fp * 2 + 1];
    float4 ba = ((const float4*)bb)[fp * 2], bc = ((const float4*)bb)[fp * 2 + 1];
    float gv[8] = {ga.x, ga.y, ga.z, ga.w, gb.x, gb.y, gb.z, gb.w};
    float bv[8] = {ba.x, ba.y, ba.z, ba.w, bc.x, bc.y, bc.z, bc.w};
#pragma unroll
    for (int t = 0; t < 8; t++) y[t] = fmaxf((v[t] - mu) * rstd * gv[t] + bv[t], 0.0f);
}

// ---------------- layer-1 gather + bias + LN + ReLU -> h1 (fp16) ----------------
__global__ __launch_bounds__(256) void gather_ln(const int* __restrict__ offs,
                                                 const int* __restrict__ degn,
                                                 const unsigned int* __restrict__ ssrc,
                                                 const float* __restrict__ di,
                                                 const __half* __restrict__ hws,
                                                 const float* __restrict__ cb,
                                                 const float* __restrict__ g,
                                                 const float* __restrict__ bb,
                                                 __half* __restrict__ out) {
    int wv = threadIdx.x >> 6;
    int lane = threadIdx.x & 63;
    int fp = lane & 7, rsub = lane >> 3;
    int node = blockIdx.x * 4 + wv;      // NN % 4 == 0
    float acc[8];
    gather_half(offs, degn, ssrc, hws, node, lane, fp, rsub, acc);
    float dn = di[node];
    float4 ca = ((const float4*)cb)[fp * 2], cc = ((const float4*)cb)[fp * 2 + 1];
    float cv[8] = {ca.x, ca.y, ca.z, ca.w, cc.x, cc.y, cc.z, cc.w};
    float v[8], y[8];
#pragma unroll
    for (int t = 0; t < 8; t++) v[t] = acc[t] * dn + cv[t];
    ln8(v, fp, g, bb, y);
    if (rsub == 0) {
        union U { float4 f4; __half2 h2[4]; } u;
#pragma unroll
        for (int t = 0; t < 4; t++) u.h2[t] = __floats2half2_rn(y[2 * t], y[2 * t + 1]);
        ((float4*)(out + (size_t)node * HD))[fp] = u.f4;
    }
}

// ---------------- layer-2 gather + LN + ReLU + skip + pooled scatter ----------------
__global__ __launch_bounds__(256) void gather_ln_pool(const int* __restrict__ offs,
                                                      const int* __restrict__ degn,
                                                      const unsigned int* __restrict__ ssrc,
                                                      const float* __restrict__ di,
                                                      const __half* __restrict__ hws,
                                                      const float* __restrict__ cb,
                                                      const float* __restrict__ g,
                                                      const float* __restrict__ bb,
                                                      const __half* __restrict__ h1,
                                                      const int* __restrict__ batch,
                                                      float* __restrict__ readout) {
    __shared__ float ls[4][HD];
    __shared__ int lb[4];
    int wv = threadIdx.x >> 6;
    int lane = threadIdx.x & 63;
    int fp = lane & 7, rsub = lane >> 3;
    int node = blockIdx.x * 4 + wv;
    float acc[8];
    gather_half(offs, degn, ssrc, hws, node, lane, fp, rsub, acc);
    float dn = di[node];
    float4 ca = ((const float4*)cb)[fp * 2], cc = ((const float4*)cb)[fp * 2 + 1];
    float cv[8] = {ca.x, ca.y, ca.z, ca.w, cc.x, cc.y, cc.z, cc.w};
    float v[8], y[8];
#pragma unroll
    for (int t = 0; t < 8; t++) v[t] = acc[t] * dn + cv[t];
    ln8(v, fp, g, bb, y);
    if (rsub == 0) {
        union U { float4 f4; __half2 h2[4]; } u;
        u.f4 = ((const float4*)(h1 + (size_t)node * HD))[fp];
        float* lrow = &ls[wv][fp * 8];
#pragma unroll
        for (int t = 0; t < 4; t++) {
            float2 p = __half22float2(u.h2[t]);
            lrow[2 * t] = y[2 * t] + p.x;
            lrow[2 * t + 1] = y[2 * t + 1] + p.y;
        }
    }
    if (lane == 0) lb[wv] = batch[node];
    __syncthreads();
    int f = lane;
    bool same = (lb[0] == lb[1]) && (lb[1] == lb[2]) && (lb[2] == lb[3]);
    if (same) {
        if (wv == 0) {
            float s4 = ls[0][f] + ls[1][f] + ls[2][f] + ls[3][f];
            atomicAdd(&readout[(size_t)lb[0] * HD + f], s4);
        }
    } else {
        atomicAdd(&readout[(size_t)lb[wv] * HD + f], ls[wv][f]);
    }
}

// ---------------- final: out = readout @ post_w + post_b  [G,64]@[64,40] ----------------
__global__ __launch_bounds__(256) void out_gemm(const float* __restrict__ r,
                                                const float* __restrict__ w,
                                                const float* __restrict__ b,
                                                float* __restrict__ out) {
    __shared__ float lw[HD * CO];
    for (int i = threadIdx.x; i < HD * CO; i += 256) lw[i] = w[i];
    __syncthreads();
    int grp = blockIdx.x * 4 + (threadIdx.x >> 6);
    int c = threadIdx.x & 63;
    if (grp >= NG || c >= CO) return;
    const float* rr = r + (size_t)grp * HD;
    float acc = b[c];
#pragma unroll 8
    for (int k = 0; k < HD; k++) acc = fmaf(rr[k], lw[k * CO + c], acc);
    out[(size_t)grp * CO + c] = acc;
}

extern "C" void kernel_launch(void* const* d_in, const int* in_sizes, int n_in,
                              void* d_out, int out_size, void* d_ws, size_t ws_size,
                              hipStream_t stream) {
    const float* x      = (const float*)d_in[0];
    const int*   ei     = (const int*)d_in[1];
    const int*   batch  = (const int*)d_in[2];
    const float* pre_w  = (const float*)d_in[3];
    const float* pre_b  = (const float*)d_in[4];
    const float* c1_w   = (const float*)d_in[5];
    const float* c1_b   = (const float*)d_in[6];
    const float* n1_g   = (const float*)d_in[7];
    const float* n1_b   = (const float*)d_in[8];
    const float* c2_w   = (const float*)d_in[9];
    const float* c2_b   = (const float*)d_in[10];
    const float* n2_g   = (const float*)d_in[11];
    const float* n2_b   = (const float*)d_in[12];
    const float* post_w = (const float*)d_in[13];
    const float* post_b = (const float*)d_in[14];

    const int* src = ei;
    const int* dst = ei + NE;

    char* p = (char*)d_ws;
    int*          ccur    = (int*)p;          p += (size_t)NBUK * 16 * 4;
    int*          offs    = (int*)p;          p += (size_t)NN * 4;
    int*          degn    = (int*)p;          p += (size_t)NN * 4;
    float*        di      = (float*)p;        p += (size_t)NN * 4;
    float*        weff    = (float*)p;        p += (size_t)FIN * HD * 4;
    float*        beff    = (float*)p;        p += 256;
    unsigned int* tmp     = (unsigned int*)p; p += (size_t)NBUK * BCAP * 4;
    unsigned int* ssrc    = (unsigned int*)p; p += (size_t)NBUK * BCAP * 4;
    float*        readout = (float*)p;        p += (size_t)NG * HD * 4;
    __half*       hws     = (__half*)p;       p += (size_t)NN * HD * 2;
    __half*       h1      = (__half*)p;       p += (size_t)NN * HD * 2;

    hipMemsetAsync(readout, 0, (size_t)NG * HD * 4, stream);

    // hierarchical CSR build (binned scatter -> per-bucket counting sort)
    init_kernel<<<(NBUK + 255) / 256, 256, 0, stream>>>(ccur);
    scatter_binned<<<NSCAT, 256, 0, stream>>>(src, dst, ccur, tmp);
    bucket_sort<<<NBUK, 256, 0, stream>>>(ccur, tmp, ssrc, offs, degn, di);

    // Folded pre-MLP weights
    weff_kernel<<<33, 256, 0, stream>>>(pre_w, pre_b, c1_w, weff, beff);

    // layer 1
    gemm1_tiled<<<768, 256, 0, stream>>>(x, weff, beff, di, hws);
    gather_ln<<<NN / 4, 256, 0, stream>>>(offs, degn, ssrc, di, hws, c1_b, n1_g, n1_b, h1);

    // layer 2
    conv_gemm_tiled<<<1280, 256, 0, stream>>>(h1, c2_w, di, hws);
    gather_ln_pool<<<NN / 4, 256, 0, stream>>>(offs, degn, ssrc, di, hws, c2_b, n2_g, n2_b, h1, batch, readout);

    out_gemm<<<(NG + 3) / 4, 256, 0, stream>>>(readout, post_w, post_b, (float*)d_out);
}